// Round 4
// baseline (341.540 us; speedup 1.0000x reference)
//
#include <hip/hip_runtime.h>

// ---------------------------------------------------------------------------
// Transformer block on MI355X. fp32 I/O (per reference), bf16 MFMA internals,
// fp32 accumulation/residuals.
// R13: (a) XCD-chunked block swizzle in all GEMMs (T1): FC2 FETCH=143MB vs
// 56MB ideal -> A-panels re-fetched per XCD. Chunked mapping gives each XCD
// 8 consecutive M-panels x all N: per-XCD A set 4MB = L2-fit. (b) fuse
// attn_combine into proj's A-staging (reg-stage A: o0+o1 scaled by
// KH_ISCALE/(l0+l1), cvt_pk to bf16, ds_write_b128; B via global_load_lds,
// counted vmcnt(10)/(2) choreography). Removes a 24MB kernel + launch.
// New ws layout (56MB min, 72MB preferred):
//   [0,16M)  Opart (flash out; fallback also w_k^T pre-flash, w_fc1^T/
//            w_fc2^T post-proj) | big: fc1o [0,32M) after proj
//   [16,24M) kh   | fallback: w_proj^T after flash, fc1o [16,32M) chunked
//   [24,32M) khT
//   [32,48M) x1 (proj out, live to FC2)
//   [48,56M) hbuf (h1/h2); lpart [48,48.5M) during flash (h1 dead)
//   [56,64M) wT1 (big only), [64,72M) wT2 (big only)
// R12 kept: BM=64 tiles for N=1024 GEMMs (4 blocks/CU). R11 kept: 2-phase
// dbuf, counted vmcnt, raw s_barrier. R10 kept: kexp folded into kh, l=P@1
// on MFMA pipe, cvt_pk P, bare v_exp_f32. R9 kept: XCD-local flash grid.
// ---------------------------------------------------------------------------

typedef __attribute__((ext_vector_type(8))) short s8v;  // 8 bf16 raw
typedef __attribute__((ext_vector_type(4))) short s4v;  // 4 bf16 raw
typedef __attribute__((ext_vector_type(4))) float f4v;  // mfma accumulator

#define D_MODEL 1024
#define SEQ 2048
#define BATCH 2
#define NH 16
#define DH 64
#define MROWS (BATCH * SEQ)

// sqrt(0.125 * log2(e)) and its inverse: kh scaled by KH_SCALE => S = qk*kexp
// straight out of the MFMA; O scaled by KH_SCALE, undone at combine.
#define KH_SCALE 0.42466088f
#define KH_ISCALE 2.3548200f

__device__ __forceinline__ float b2f(unsigned short u) {
  union { unsigned int i; float f; } v; v.i = ((unsigned int)u) << 16; return v.f;
}
__device__ __forceinline__ unsigned short f2b(float f) {
  unsigned int i = __builtin_bit_cast(unsigned int, f);
  unsigned int r = (i + 0x7fffu + ((i >> 16) & 1u)) >> 16;  // RNE
  return (unsigned short)r;
}
// async global->LDS, 16B/lane; dest = wave-uniform base + lane*16 (m104/m108)
__device__ __forceinline__ void async16(const void* g, void* l) {
  __builtin_amdgcn_global_load_lds(
      (const __attribute__((address_space(1))) unsigned int*)g,
      (__attribute__((address_space(3))) unsigned int*)l, 16, 0, 0);
}
__device__ __forceinline__ unsigned short cvt_b(float f) { return f2b(f); }
__device__ __forceinline__ unsigned short cvt_b(unsigned short u) { return u; }

// bare v_exp_f32 (exp2); OCML exp2f adds range-check overhead
__device__ __forceinline__ float xp2(float x) {
#if __has_builtin(__builtin_amdgcn_exp2f)
  return __builtin_amdgcn_exp2f(x);
#else
  return exp2f(x);
#endif
}

// 4x f32 -> packed bf16 s4v via v_cvt_pk_bf16_f32 (RNE, 2 instructions).
__device__ __forceinline__ s4v cvt4(float a, float b, float c, float d) {
  unsigned int lo, hi;
  asm("v_cvt_pk_bf16_f32 %0, %1, %2" : "=v"(lo) : "v"(a), "v"(b));
  asm("v_cvt_pk_bf16_f32 %0, %1, %2" : "=v"(hi) : "v"(c), "v"(d));
  union { unsigned long long u; s4v v; } u;
  u.u = ((unsigned long long)hi << 32) | (unsigned long long)lo;
  return u.v;
}

// K=16 bf16 mfma: prefer native; fall back to zero-padded K=32.
#if __has_builtin(__builtin_amdgcn_mfma_f32_16x16x16_bf16)
__device__ __forceinline__ f4v mfma16(s4v a, s4v b, f4v c) {
  return __builtin_amdgcn_mfma_f32_16x16x16_bf16(a, b, c, 0, 0, 0);
}
#elif __has_builtin(__builtin_amdgcn_mfma_f32_16x16x16bf16_1k)
__device__ __forceinline__ f4v mfma16(s4v a, s4v b, f4v c) {
  return __builtin_amdgcn_mfma_f32_16x16x16bf16_1k(a, b, c, 0, 0, 0);
}
#else
__device__ __forceinline__ f4v mfma16(s4v a, s4v b, f4v c) {
  s8v aa = {a[0], a[1], a[2], a[3], 0, 0, 0, 0};
  s8v bb = {b[0], b[1], b[2], b[3], 0, 0, 0, 0};
  return __builtin_amdgcn_mfma_f32_16x16x32_bf16(aa, bb, c, 0, 0, 0);
}
#endif

// XCD-chunked logical block id (T1): physical id p lands on XCD p%8; give
// each XCD a contiguous logical chunk so co-resident blocks share A-panels.
__device__ __forceinline__ int xcd_swz(int bidl, int nwg) {
  return (nwg & 7) ? bidl : ((bidl & 7) * (nwg >> 3) + (bidl >> 3));
}

// ---------------- LayerNorm: fp32 in -> bf16 out, one block per row ---------
__global__ __launch_bounds__(256) void ln_kernel(
    const float* __restrict__ x, const float* __restrict__ g,
    const float* __restrict__ bb, unsigned short* __restrict__ out) {
  int row = blockIdx.x;
  int t = threadIdx.x;
  const float* xr = x + (size_t)row * D_MODEL;
  float v[4];
  float s = 0.f, s2 = 0.f;
#pragma unroll
  for (int i = 0; i < 4; ++i) {
    float f = xr[t + 256 * i];
    v[i] = f; s += f; s2 += f * f;
  }
#pragma unroll
  for (int off = 1; off < 64; off <<= 1) {
    s += __shfl_xor(s, off, 64);
    s2 += __shfl_xor(s2, off, 64);
  }
  __shared__ float red[8];
  if ((t & 63) == 0) { red[t >> 6] = s; red[4 + (t >> 6)] = s2; }
  __syncthreads();
  s = red[0] + red[1] + red[2] + red[3];
  s2 = red[4] + red[5] + red[6] + red[7];
  float mu = s * (1.f / D_MODEL);
  float var = s2 * (1.f / D_MODEL) - mu * mu;
  float rstd = rsqrtf(var + 1e-5f);
#pragma unroll
  for (int i = 0; i < 4; ++i) {
    int c = t + 256 * i;
    float h = (v[i] - mu) * rstd * g[c] + bb[c];
    out[(size_t)row * D_MODEL + c] = f2b(h);
  }
}

// ---------------- batched 64x64 tile transpose -> bf16 ----------------------
template <typename T>
__global__ __launch_bounds__(256) void transpose_b(
    const T* __restrict__ src, unsigned short* __restrict__ dst,
    int srcStride, int dstStride, long long srcBatch, long long dstBatch) {
  __shared__ unsigned short tile[64][65];
  const T* s = src + (size_t)blockIdx.z * srcBatch;
  unsigned short* d = dst + (size_t)blockIdx.z * dstBatch;
  int n0 = blockIdx.x * 64, k0 = blockIdx.y * 64;
  for (int i = threadIdx.x; i < 4096; i += 256) {
    int k = i >> 6, n = i & 63;
    tile[k][n] = cvt_b(s[(size_t)(k0 + k) * srcStride + n0 + n]);
  }
  __syncthreads();
  for (int i = threadIdx.x; i < 4096; i += 256) {
    int n = i >> 6, k = i & 63;
    d[(size_t)(n0 + n) * dstStride + k0 + k] = tile[k][n];
  }
}

// ---------------- GEMM: C[M,N] = A[M,K] @ Bt[N,K]^T + bias (+res)(+relu) ----
// BMxBN tile, BK=64, 4 waves (2x2) each (BM/2)x(BN/2).
// 2-phase dbuf staging, counted vmcnt, raw s_barrier; XCD-chunked swizzle.
// LDS [row][64] bf16 with 16B-chunk XOR swizzle; global_load_lds width=16.
// KH path additionally scales output by KH_SCALE (softmax pre-scale, R10).
template <int RES, bool RELU, bool KH, int OUTF, int BM, int BN>
__global__ __launch_bounds__(256) void gemm_bt(
    const unsigned short* __restrict__ A, const unsigned short* __restrict__ Bt,
    const float* __restrict__ bias, const float* __restrict__ res,
    void* __restrict__ out, int M, int N, int K) {
  constexpr int MT = BM / 32;  // M frag-tiles per wave
  constexpr int NT = BN / 32;  // N frag-tiles per wave
  __shared__ __align__(16) unsigned short lsA[2][BM * 64];
  __shared__ __align__(16) unsigned short lsB[2][BN * 64];
  int tid = threadIdx.x;
  int lane = tid & 63, w = tid >> 6, quad = lane >> 4, l16 = lane & 15;
  int bidl = blockIdx.y * (int)gridDim.x + blockIdx.x;
  int swz = xcd_swz(bidl, (int)(gridDim.x * gridDim.y));
  int m0 = (swz / (int)gridDim.x) * BM, n0 = (swz % (int)gridDim.x) * BN;
  int wm = (w >> 1) * (BM / 2), wn = (w & 1) * (BN / 2);
  f4v acc[MT][NT] = {};

  // issue one K-tile's staging loads (async, MT + NT async16 per wave)
  auto stage = [&](int bsel, int ktE) {
#pragma unroll
    for (int i = 0; i < MT; ++i) {
      int cb = w * (BM * 2) + i * 64;
      int ci = cb + lane;
      int row = ci >> 3, c = ci & 7;
      int cs = c ^ (row & 7);
      async16(A + (size_t)(m0 + row) * K + ktE + cs * 8, &lsA[bsel][cb * 8]);
    }
#pragma unroll
    for (int i = 0; i < NT; ++i) {
      int cb = w * (BN * 2) + i * 64;
      int ci = cb + lane;
      int row = ci >> 3, c = ci & 7;
      int cs = c ^ (row & 7);
      async16(Bt + (size_t)(n0 + row) * K + ktE + cs * 8, &lsB[bsel][cb * 8]);
    }
  };

  stage(0, 0);
  int nK = K >> 6;
  for (int kt = 0; kt < nK; ++kt) {
    int b = kt & 1;
    if (kt + 1 < nK) {
      stage(b ^ 1, (kt + 1) << 6);  // prefetch next tile (stays in flight)
      if constexpr (MT + NT == 4)      asm volatile("s_waitcnt vmcnt(4)" ::: "memory");
      else if constexpr (MT + NT == 6) asm volatile("s_waitcnt vmcnt(6)" ::: "memory");
      else                             asm volatile("s_waitcnt vmcnt(8)" ::: "memory");
    } else {
      asm volatile("s_waitcnt vmcnt(0)" ::: "memory");
    }
    __builtin_amdgcn_sched_barrier(0);
    __builtin_amdgcn_s_barrier();   // all waves' tile-kt loads landed
    __builtin_amdgcn_sched_barrier(0);
#pragma unroll
    for (int s = 0; s < 2; ++s) {
      s8v af[MT], bf[NT];
#pragma unroll
      for (int t = 0; t < MT; ++t) {
        int am = wm + t * 16 + l16;
        int ac = (s * 4 + quad) ^ (am & 7);
        af[t] = *(const s8v*)(&lsA[b][am * 64 + ac * 8]);
      }
#pragma unroll
      for (int t = 0; t < NT; ++t) {
        int bn = wn + t * 16 + l16;
        int bc = (s * 4 + quad) ^ (bn & 7);
        bf[t] = *(const s8v*)(&lsB[b][bn * 64 + bc * 8]);
      }
#pragma unroll
      for (int ti = 0; ti < MT; ++ti)
#pragma unroll
        for (int tj = 0; tj < NT; ++tj)
          acc[ti][tj] = __builtin_amdgcn_mfma_f32_16x16x32_bf16(
              af[ti], bf[tj], acc[ti][tj], 0, 0, 0);
    }
    // WAR: my ds_reads of buf b must complete before others overwrite it
    asm volatile("s_waitcnt lgkmcnt(0)" ::: "memory");
    __builtin_amdgcn_sched_barrier(0);
    __builtin_amdgcn_s_barrier();
    __builtin_amdgcn_sched_barrier(0);
  }
  // epilogue: C/D layout col=lane&15, row=quad*4+r  (m89/m91-verified)
#pragma unroll
  for (int tj = 0; tj < NT; ++tj) {
    int col = n0 + wn + tj * 16 + l16;
    float bv = bias[col];
#pragma unroll
    for (int ti = 0; ti < MT; ++ti) {
#pragma unroll
      for (int r = 0; r < 4; ++r) {
        int rowg = m0 + wm + ti * 16 + quad * 4 + r;
        float vv = acc[ti][tj][r] + bv;
        if (KH) vv *= KH_SCALE;  // pre-scale S by kexp (R10)
        if (RES == 2) vv += res[(size_t)rowg * N + col];
        if (RELU) vv = fmaxf(vv, 0.f);
        size_t oidx;
        if (KH) {
          int b2 = rowg >> 11, l = rowg & 2047, h = col >> 6, d = col & 63;
          oidx = (((size_t)(b2 * NH + h)) * SEQ + l) * DH + d;
        } else {
          oidx = (size_t)rowg * N + col;
        }
        if (OUTF == 0) ((unsigned short*)out)[oidx] = f2b(vv);
        else           ((float*)out)[oidx] = vv;
      }
    }
  }
}

// ---------------- proj GEMM with fused attention-combine A-staging ----------
// x1[M,N] = ((O0+O1)/l) @ w_proj^T + b + x.  BM=BN=64, MT=NT=2, K=1024.
// A is built on the fly: reg-load both bf16 O-partials + lpart, scale by
// KH_ISCALE/(l0+l1), cvt_pk to bf16, ds_write_b128 (same chunk XOR swizzle).
// K-step kt covers exactly head kt (BK=64=DH), so lpart index head = kt.
// vmcnt: per step issue 8 A-reg loads + 2 B async16. vmcnt(10) before the
// compute barrier drains prev-tile's 2 B async16; vmcnt(2) after compute
// waits this-issue A-regs (B stays in flight).
__global__ __launch_bounds__(256) void gemm_proj(
    const unsigned short* __restrict__ Opart, const float* __restrict__ lpart,
    const unsigned short* __restrict__ Bt, const float* __restrict__ bias,
    const float* __restrict__ res, float* __restrict__ out, int M, int N, int K) {
  __shared__ __align__(16) unsigned short lsA[2][64 * 64];
  __shared__ __align__(16) unsigned short lsB[2][64 * 64];
  int tid = threadIdx.x;
  int lane = tid & 63, w = tid >> 6, quad = lane >> 4, l16 = lane & 15;
  int bidl = blockIdx.y * (int)gridDim.x + blockIdx.x;
  int swz = xcd_swz(bidl, (int)(gridDim.x * gridDim.y));
  int m0 = (swz / (int)gridDim.x) * 64, n0 = (swz % (int)gridDim.x) * 64;
  int wm = (w >> 1) * 32, wn = (w & 1) * 32;
  f4v acc[2][2] = {};

  // per-lane A-chunk geometry (fixed across K-steps)
  int ci_[2], csA[2], mA[2], b2A[2], lA[2];
#pragma unroll
  for (int i = 0; i < 2; ++i) {
    int cb = w * 128 + i * 64;
    int ci = cb + lane;
    int row = ci >> 3, c = ci & 7;
    ci_[i] = ci; csA[i] = c ^ (row & 7);
    mA[i] = m0 + row; b2A[i] = mA[i] >> 11; lA[i] = mA[i] & 2047;
  }
  s8v o0r[2], o1r[2];
  float lsr0[2], lsr1[2];
  auto issueA = [&](int kt) {
#pragma unroll
    for (int i = 0; i < 2; ++i) {
      const unsigned short* pa =
          Opart + (size_t)mA[i] * D_MODEL + kt * 64 + csA[i] * 8;
      o0r[i] = *(const s8v*)pa;
      o1r[i] = *(const s8v*)(pa + (size_t)MROWS * D_MODEL);
      size_t lidx = ((size_t)b2A[i] * NH + kt) * SEQ + lA[i];
      lsr0[i] = lpart[lidx];
      lsr1[i] = lpart[(size_t)BATCH * NH * SEQ + lidx];
    }
  };
  auto issueB = [&](int bsel, int ktE) {
#pragma unroll
    for (int i = 0; i < 2; ++i) {
      int cb = w * 128 + i * 64;
      int ci = cb + lane;
      int row = ci >> 3, c = ci & 7;
      int cs = c ^ (row & 7);
      async16(Bt + (size_t)(n0 + row) * K + ktE + cs * 8, &lsB[bsel][cb * 8]);
    }
  };
  auto combineWrite = [&](int bsel) {
#pragma unroll
    for (int i = 0; i < 2; ++i) {
      float inv = KH_ISCALE / (lsr0[i] + lsr1[i]);
      float f[8];
#pragma unroll
      for (int j = 0; j < 8; ++j)
        f[j] = (b2f((unsigned short)o0r[i][j]) +
                b2f((unsigned short)o1r[i][j])) * inv;
      s4v lo = cvt4(f[0], f[1], f[2], f[3]);
      s4v hi = cvt4(f[4], f[5], f[6], f[7]);
      s8v vv = {lo[0], lo[1], lo[2], lo[3], hi[0], hi[1], hi[2], hi[3]};
      *(s8v*)(&lsA[bsel][ci_[i] * 8]) = vv;
    }
  };

  // prologue: tile 0
  issueA(0); issueB(0, 0);
  __builtin_amdgcn_sched_barrier(0);
  asm volatile("s_waitcnt vmcnt(2)" ::: "memory");  // A-regs done, B0 flying
  __builtin_amdgcn_sched_barrier(0);
  combineWrite(0);
  asm volatile("s_waitcnt lgkmcnt(0)" ::: "memory");
  __builtin_amdgcn_sched_barrier(0);

  int nK = K >> 6;
  for (int kt = 0; kt < nK; ++kt) {
    int b = kt & 1;
    if (kt + 1 < nK) {
      issueA(kt + 1); issueB(b ^ 1, (kt + 1) << 6);
      __builtin_amdgcn_sched_barrier(0);
      asm volatile("s_waitcnt vmcnt(10)" ::: "memory");  // prev B drained
    } else {
      __builtin_amdgcn_sched_barrier(0);
      asm volatile("s_waitcnt vmcnt(0)" ::: "memory");
    }
    __builtin_amdgcn_sched_barrier(0);
    __builtin_amdgcn_s_barrier();  // tile kt (A ds_writes + B async16) ready
    __builtin_amdgcn_sched_barrier(0);
#pragma unroll
    for (int s = 0; s < 2; ++s) {
      s8v af[2], bf[2];
#pragma unroll
      for (int t = 0; t < 2; ++t) {
        int am = wm + t * 16 + l16;
        int ac = (s * 4 + quad) ^ (am & 7);
        af[t] = *(const s8v*)(&lsA[b][am * 64 + ac * 8]);
      }
#pragma unroll
      for (int t = 0; t < 2; ++t) {
        int bn = wn + t * 16 + l16;
        int bc = (s * 4 + quad) ^ (bn & 7);
        bf[t] = *(const s8v*)(&lsB[b][bn * 64 + bc * 8]);
      }
#pragma unroll
      for (int ti = 0; ti < 2; ++ti)
#pragma unroll
        for (int tj = 0; tj < 2; ++tj)
          acc[ti][tj] = __builtin_amdgcn_mfma_f32_16x16x32_bf16(
              af[ti], bf[tj], acc[ti][tj], 0, 0, 0);
    }
    if (kt + 1 < nK) {
      __builtin_amdgcn_sched_barrier(0);
      asm volatile("s_waitcnt vmcnt(2)" ::: "memory");  // next A-regs landed
      __builtin_amdgcn_sched_barrier(0);
      combineWrite(b ^ 1);
    }
    asm volatile("s_waitcnt lgkmcnt(0)" ::: "memory");
    __builtin_amdgcn_sched_barrier(0);
    __builtin_amdgcn_s_barrier();
    __builtin_amdgcn_sched_barrier(0);
  }
  // epilogue: bias + residual, fp32 out
#pragma unroll
  for (int tj = 0; tj < 2; ++tj) {
    int col = n0 + wn + tj * 16 + l16;
    float bv = bias[col];
#pragma unroll
    for (int ti = 0; ti < 2; ++ti) {
#pragma unroll
      for (int r = 0; r < 4; ++r) {
        int rowg = m0 + wm + ti * 16 + quad * 4 + r;
        float vv = acc[ti][tj][r] + bv + res[(size_t)rowg * N + col];
        out[(size_t)rowg * N + col] = vv;
      }
    }
  }
}

// ---------------- fused flash attention, register-P, XCD-local --------------
// grid (split=2, bh=32, qb=16): linear id = 64*qb + 2*bh + split => id%8 =
// (2bh+split)%8 -> all qb-blocks of a (bh,split) pair share an XCD; per-XCD
// working set = 8 pairs x 256KB = 2MB <= 4MB L2.
// 128-key staging tiles, processed as 2x64-key halves.
// S^T = mfma(K,Q): exp'd C-frag IS a K=16 A-operand (register P, no LDS trip).
// R10: kh pre-scaled by sqrt(kexp) => exp2 directly on accST; P->bf16 via
// v_cvt_pk_bf16_f32; l = P @ ones on the MFMA pipe (accL).
__global__ __launch_bounds__(256) void flash_k(
    const unsigned short* __restrict__ kh, const unsigned short* __restrict__ khT,
    unsigned short* __restrict__ Opart, float* __restrict__ lpart) {
  __shared__ __align__(16) unsigned short lsK[128 * 64];   // [key][d], 8-chunk rows
  __shared__ __align__(16) unsigned short lsKT[64 * 128];  // [d][key], 16-chunk rows
  int tid = threadIdx.x;
  int lane = tid & 63, w = tid >> 6, quad = lane >> 4, l16 = lane & 15;
  int split = blockIdx.x, bh = blockIdx.y, qb = blockIdx.z;
  const unsigned short* khB = kh + (size_t)bh * SEQ * DH;
  const unsigned short* khTB = khT + (size_t)bh * DH * SEQ;
  unsigned short* Op = Opart + (size_t)split * MROWS * D_MODEL;
  float* lp = lpart + (size_t)split * BATCH * NH * SEQ;
  s8v aQ[2][2];
#pragma unroll
  for (int g = 0; g < 2; ++g) {
    int q = qb * 128 + w * 32 + g * 16 + l16;
#pragma unroll
    for (int s = 0; s < 2; ++s)
      aQ[g][s] = *(const s8v*)(khB + (size_t)q * DH + s * 32 + quad * 8);
  }
  const s4v vone = {(short)0x3F80, (short)0x3F80, (short)0x3F80, (short)0x3F80};
  f4v accO[2][4] = {};
  f4v accL[2] = {};  // row q = quad*4+r (col-replicated): l-sums via MFMA

  for (int kt8 = 0; kt8 < 8; ++kt8) {
    int key0 = split * 1024 + kt8 * 128;
    // stage lsK (128 keys x 64 d): 1024 chunks, 4 async16/wave
#pragma unroll
    for (int i = 0; i < 4; ++i) {
      int cb = w * 256 + i * 64;
      int ci = cb + lane;
      int row = ci >> 3, c = ci & 7;
      int cs = c ^ (row & 7);
      async16(khB + (size_t)(key0 + row) * DH + cs * 8, &lsK[cb * 8]);
    }
    // stage lsKT (64 d x 128 keys): 1024 chunks, 16-slot swizzle
#pragma unroll
    for (int i = 0; i < 4; ++i) {
      int cb = w * 256 + i * 64;
      int ci = cb + lane;
      int row = ci >> 4, c = ci & 15;
      int cs = c ^ (row & 15);
      async16(khTB + (size_t)row * SEQ + key0 + cs * 8, &lsKT[cb * 8]);
    }
    __builtin_amdgcn_s_waitcnt(0x0f70);  // vmcnt(0)
    __syncthreads();
#pragma unroll
    for (int half = 0; half < 2; ++half) {
      // S^T = K @ Q^T over 64 keys (lane = key within sub-tile)
      f4v accST[2][4] = {};
#pragma unroll
      for (int s = 0; s < 2; ++s) {
#pragma unroll
        for (int tj = 0; tj < 4; ++tj) {
          int key = half * 64 + tj * 16 + l16;
          int c = (s * 4 + quad) ^ (key & 7);
          s8v kf = *(const s8v*)(&lsK[key * 64 + c * 8]);
#pragma unroll
          for (int g = 0; g < 2; ++g)
            accST[g][tj] = __builtin_amdgcn_mfma_f32_16x16x32_bf16(
                kf, aQ[g][s], accST[g][tj], 0, 0, 0);
        }
      }
      // exp in-register -> P A-frags (cvt_pk RNE); l via MFMA; PV from lsKT
#pragma unroll
      for (int tj = 0; tj < 4; ++tj) {
        s4v pf[2];
#pragma unroll
        for (int g = 0; g < 2; ++g) {
          float p0 = xp2(accST[g][tj][0]);
          float p1 = xp2(accST[g][tj][1]);
          float p2 = xp2(accST[g][tj][2]);
          float p3 = xp2(accST[g][tj][3]);
          pf[g] = cvt4(p0, p1, p2, p3);
          accL[g] = mfma16(pf[g], vone, accL[g]);  // l-sum on MFMA pipe
        }
#pragma unroll
        for (int db = 0; db < 4; ++db) {
          int d = db * 16 + l16;
          int ch = (half * 8 + tj * 2 + (quad >> 1)) ^ (d & 15);
          s4v vf = *(const s4v*)(&lsKT[d * 128 + ch * 8 + (quad & 1) * 4]);
#pragma unroll
          for (int g = 0; g < 2; ++g)
            accO[g][db] = mfma16(pf[g], vf, accO[g][db]);
        }
      }
    }
    __syncthreads();
  }
  // epilogue: accL rows = q (quad*4+r), cols replicated -> l16==0 lanes write
  int b = bh >> 4, h = bh & 15;
#pragma unroll
  for (int g = 0; g < 2; ++g) {
    if (l16 == 0) {
#pragma unroll
      for (int r = 0; r < 4; ++r) {
        int q = qb * 128 + w * 32 + g * 16 + quad * 4 + r;
        lp[(size_t)bh * SEQ + q] = accL[g][r];
      }
    }
#pragma unroll
    for (int r = 0; r < 4; ++r) {
      int l = qb * 128 + w * 32 + g * 16 + quad * 4 + r;
#pragma unroll
      for (int db = 0; db < 4; ++db) {
        int d = db * 16 + l16;
        Op[((size_t)(b * SEQ + l)) * D_MODEL + h * DH + d] = f2b(accO[g][db][r]);
      }
    }
  }
}

// ---------------------------------------------------------------------------
extern "C" void kernel_launch(void* const* d_in, const int* in_sizes, int n_in,
                              void* d_out, int out_size, void* d_ws, size_t ws_size,
                              hipStream_t stream) {
  (void)in_sizes; (void)n_in; (void)out_size;
  const float* x      = (const float*)d_in[0];
  const float* w_attn = (const float*)d_in[1];
  const float* b_attn = (const float*)d_in[2];
  const float* w_proj = (const float*)d_in[3];
  const float* b_proj = (const float*)d_in[4];
  const float* ln1_g  = (const float*)d_in[5];
  const float* ln1_b  = (const float*)d_in[6];
  const float* ln2_g  = (const float*)d_in[7];
  const float* ln2_b  = (const float*)d_in[8];
  const float* w_fc1  = (const float*)d_in[9];
  const float* b_fc1  = (const float*)d_in[10];
  const float* w_fc2  = (const float*)d_in[11];
  const float* b_fc2  = (const float*)d_in[12];

  char* ws = (char*)d_ws;
  unsigned short* Opart = (unsigned short*)ws;                       // [0,16M)
  unsigned short* kh    = (unsigned short*)(ws + (size_t)(16u << 20)); // [16,24)
  unsigned short* khT   = (unsigned short*)(ws + (size_t)(24u << 20)); // [24,32)
  float*          x1    = (float*)(ws + (size_t)(32u << 20));          // [32,48)
  unsigned short* hbuf  = (unsigned short*)(ws + (size_t)(48u << 20)); // [48,56)
  float*          lpart = (float*)(ws + (size_t)(48u << 20));  // h1 dead by flash
  float* outf = (float*)d_out;
  bool big_ws = ws_size >= ((size_t)72u << 20);

  // weight-transpose + fc1o slots differ by ws size (lifetime-packed)
  unsigned short* wTk;    // w_k^T      (live: steps 2-3, pre-flash)
  unsigned short* wTp;    // w_proj^T   (live: post-flash, proj)
  unsigned short* wTf1;   // w_fc1^T    (live: post-proj)
  unsigned short* wTf2;   // w_fc2^T    (live: post-proj)
  unsigned short* fc1o;
  if (big_ws) {
    wTk  = (unsigned short*)(ws + (size_t)(56u << 20));
    wTp  = wTk;                                            // same slot, serial
    wTf1 = wTk;
    wTf2 = (unsigned short*)(ws + (size_t)(64u << 20));
    fc1o = (unsigned short*)ws;                            // [0,32): Op/kh/khT dead
  } else {
    wTk  = (unsigned short*)ws;                            // [0,8): pre-Opart
    wTp  = kh;                                             // [16,24): kh dead post-flash
    wTf1 = (unsigned short*)ws;                            // [0,8): Opart dead post-proj
    wTf2 = (unsigned short*)(ws + (size_t)(8u << 20));     // [8,16)
    fc1o = kh;                                             // [16,32): chunked 16MB
  }

  dim3 blk(256);
  // 1. h1 = LN1(x)
  hipLaunchKernelGGL(ln_kernel, dim3(MROWS), blk, 0, stream, x, ln1_g, ln1_b, hbuf);
  // 2. wTk = (w_attn[:, 1024:2048])^T  (only the K slice is ever used)
  hipLaunchKernelGGL(transpose_b<float>, dim3(16, 16, 1), blk, 0, stream,
                     w_attn + 1024, wTk, 3 * D_MODEL, D_MODEL, 0LL, 0LL);
  // 3. kh[b,h,l,d] = (h1 @ w_k + b_k) * KH_SCALE   (BM=64 -> 1024 blocks)
  hipLaunchKernelGGL((gemm_bt<0, false, true, 0, 64, 64>), dim3(16, 64), blk, 0,
                     stream, hbuf, wTk, b_attn + 1024, nullptr, (void*)kh,
                     MROWS, D_MODEL, D_MODEL);
  // 4. khT[b,h,d,l] = transpose(kh) per head
  hipLaunchKernelGGL(transpose_b<unsigned short>, dim3(1, 32, 32), blk, 0, stream,
                     kh, khT, DH, SEQ, (long long)(SEQ * DH), (long long)(DH * SEQ));
  // 5. flash (XCD-local grid) -> bf16 unnormalized partials + l partials
  hipLaunchKernelGGL(flash_k, dim3(2, 32, SEQ / 128), blk, 0, stream,
                     kh, khT, Opart, lpart);
  // 6. wTp = w_proj^T ; x1 = combine(Opart,lpart) @ w_proj + b + x  (fused)
  hipLaunchKernelGGL(transpose_b<float>, dim3(16, 16, 1), blk, 0, stream,
                     w_proj, wTp, D_MODEL, D_MODEL, 0LL, 0LL);
  hipLaunchKernelGGL(gemm_proj, dim3(16, 64), blk, 0, stream,
                     Opart, lpart, wTp, b_proj, x, x1,
                     MROWS, D_MODEL, D_MODEL);
  // 7. h2 = LN2(x1)
  hipLaunchKernelGGL(ln_kernel, dim3(MROWS), blk, 0, stream, x1, ln2_g, ln2_b, hbuf);
  // 8. wTf1 = w_fc1^T ; wTf2 = w_fc2^T
  hipLaunchKernelGGL(transpose_b<float>, dim3(64, 16, 1), blk, 0, stream,
                     w_fc1, wTf1, 4 * D_MODEL, D_MODEL, 0LL, 0LL);
  hipLaunchKernelGGL(transpose_b<float>, dim3(16, 64, 1), blk, 0, stream,
                     w_fc2, wTf2, D_MODEL, 4 * D_MODEL, 0LL, 0LL);
  // 9/10. FFN: FC1 BM=128 (2048 blocks); FC2 BM=64 (1024 blocks)
  if (big_ws) {
    hipLaunchKernelGGL((gemm_bt<0, true, false, 0, 128, 64>), dim3(64, 32), blk, 0,
                       stream, hbuf, wTf1, b_fc1, nullptr, (void*)fc1o,
                       MROWS, 4 * D_MODEL, D_MODEL);
    hipLaunchKernelGGL((gemm_bt<2, false, false, 1, 64, 64>), dim3(16, 64), blk, 0,
                       stream, fc1o, wTf2, b_fc2, x1, (void*)outf,
                       MROWS, D_MODEL, 4 * D_MODEL);
  } else {
    for (int c = 0; c < 2; ++c) {
      const unsigned short* h2c = hbuf + (size_t)c * 2048 * D_MODEL;
      const float* x1c = x1 + (size_t)c * 2048 * D_MODEL;
      float* outc = outf + (size_t)c * 2048 * D_MODEL;
      hipLaunchKernelGGL((gemm_bt<0, true, false, 0, 128, 64>), dim3(64, 16), blk, 0,
                         stream, h2c, wTf1, b_fc1, nullptr, (void*)fc1o,
                         2048, 4 * D_MODEL, D_MODEL);
      hipLaunchKernelGGL((gemm_bt<2, false, false, 1, 64, 64>), dim3(16, 32), blk, 0,
                         stream, fc1o, wTf2, b_fc2, x1c, (void*)outc,
                         2048, D_MODEL, 4 * D_MODEL);
    }
  }
}

// Round 5
// 331.442 us; speedup vs baseline: 1.0305x; 1.0305x over previous
//
#include <hip/hip_runtime.h>

// ---------------------------------------------------------------------------
// Transformer block on MI355X. fp32 I/O (per reference), bf16 MFMA internals,
// fp32 accumulation/residuals.
// R14: 256x256 8-phase GEMM (T3+T4+T5) for FC1. R13 post-mortem: FC1 is the
// profile head (57us, MfmaUtil 24%); 2-phase covers ~600cyc of ~900cyc miss
// latency; m233: 2-phase critical path = stage+vmcnt+barrier. 8-phase with
// counted vmcnt(4) at ph4/ph8 only keeps 2-6 half-tiles in flight, never
// drains; setprio(1) around MFMA clusters pays only on this structure (T5).
// Geometry: 256x256 tile, BK=64, 8 waves (2Mx4N), per-wave 128x64, LDS 128KB
// = 1 block/CU, grid 16x16=256 = exactly 1/CU. Quadrant order (mh,nh) =
// 00,10,01,11; half-buffers split by quadrant (not wave-row) so each frees
// after 2 barrier-separated phases; stage order derived from free times.
// R13 kept: XCD-chunked swizzle, fused combine-proj, ws lifetime packing.
// R12 kept: BM=64 for N=1024 GEMMs. R11: 2-phase dbuf elsewhere. R10: kexp
// in kh, l=P@1 MFMA, cvt_pk, bare exp2. R9: XCD-local flash grid.
// ws layout unchanged from R13.
// ---------------------------------------------------------------------------

typedef __attribute__((ext_vector_type(8))) short s8v;  // 8 bf16 raw
typedef __attribute__((ext_vector_type(4))) short s4v;  // 4 bf16 raw
typedef __attribute__((ext_vector_type(4))) float f4v;  // mfma accumulator

#define D_MODEL 1024
#define SEQ 2048
#define BATCH 2
#define NH 16
#define DH 64
#define MROWS (BATCH * SEQ)

#define KH_SCALE 0.42466088f
#define KH_ISCALE 2.3548200f

__device__ __forceinline__ float b2f(unsigned short u) {
  union { unsigned int i; float f; } v; v.i = ((unsigned int)u) << 16; return v.f;
}
__device__ __forceinline__ unsigned short f2b(float f) {
  unsigned int i = __builtin_bit_cast(unsigned int, f);
  unsigned int r = (i + 0x7fffu + ((i >> 16) & 1u)) >> 16;  // RNE
  return (unsigned short)r;
}
// async global->LDS, 16B/lane; dest = wave-uniform base + lane*16 (m104/m108)
__device__ __forceinline__ void async16(const void* g, void* l) {
  __builtin_amdgcn_global_load_lds(
      (const __attribute__((address_space(1))) unsigned int*)g,
      (__attribute__((address_space(3))) unsigned int*)l, 16, 0, 0);
}
__device__ __forceinline__ unsigned short cvt_b(float f) { return f2b(f); }
__device__ __forceinline__ unsigned short cvt_b(unsigned short u) { return u; }

__device__ __forceinline__ float xp2(float x) {
#if __has_builtin(__builtin_amdgcn_exp2f)
  return __builtin_amdgcn_exp2f(x);
#else
  return exp2f(x);
#endif
}

// 4x f32 -> packed bf16 s4v via v_cvt_pk_bf16_f32 (RNE, 2 instructions).
__device__ __forceinline__ s4v cvt4(float a, float b, float c, float d) {
  unsigned int lo, hi;
  asm("v_cvt_pk_bf16_f32 %0, %1, %2" : "=v"(lo) : "v"(a), "v"(b));
  asm("v_cvt_pk_bf16_f32 %0, %1, %2" : "=v"(hi) : "v"(c), "v"(d));
  union { unsigned long long u; s4v v; } u;
  u.u = ((unsigned long long)hi << 32) | (unsigned long long)lo;
  return u.v;
}

#if __has_builtin(__builtin_amdgcn_mfma_f32_16x16x16_bf16)
__device__ __forceinline__ f4v mfma16(s4v a, s4v b, f4v c) {
  return __builtin_amdgcn_mfma_f32_16x16x16_bf16(a, b, c, 0, 0, 0);
}
#elif __has_builtin(__builtin_amdgcn_mfma_f32_16x16x16bf16_1k)
__device__ __forceinline__ f4v mfma16(s4v a, s4v b, f4v c) {
  return __builtin_amdgcn_mfma_f32_16x16x16bf16_1k(a, b, c, 0, 0, 0);
}
#else
__device__ __forceinline__ f4v mfma16(s4v a, s4v b, f4v c) {
  s8v aa = {a[0], a[1], a[2], a[3], 0, 0, 0, 0};
  s8v bb = {b[0], b[1], b[2], b[3], 0, 0, 0, 0};
  return __builtin_amdgcn_mfma_f32_16x16x32_bf16(aa, bb, c, 0, 0, 0);
}
#endif

// XCD-chunked logical block id (T1); bijective only when nwg%8==0.
__device__ __forceinline__ int xcd_swz(int bidl, int nwg) {
  return (nwg & 7) ? bidl : ((bidl & 7) * (nwg >> 3) + (bidl >> 3));
}

// ---------------- LayerNorm: fp32 in -> bf16 out, one block per row ---------
__global__ __launch_bounds__(256) void ln_kernel(
    const float* __restrict__ x, const float* __restrict__ g,
    const float* __restrict__ bb, unsigned short* __restrict__ out) {
  int row = blockIdx.x;
  int t = threadIdx.x;
  const float* xr = x + (size_t)row * D_MODEL;
  float v[4];
  float s = 0.f, s2 = 0.f;
#pragma unroll
  for (int i = 0; i < 4; ++i) {
    float f = xr[t + 256 * i];
    v[i] = f; s += f; s2 += f * f;
  }
#pragma unroll
  for (int off = 1; off < 64; off <<= 1) {
    s += __shfl_xor(s, off, 64);
    s2 += __shfl_xor(s2, off, 64);
  }
  __shared__ float red[8];
  if ((t & 63) == 0) { red[t >> 6] = s; red[4 + (t >> 6)] = s2; }
  __syncthreads();
  s = red[0] + red[1] + red[2] + red[3];
  s2 = red[4] + red[5] + red[6] + red[7];
  float mu = s * (1.f / D_MODEL);
  float var = s2 * (1.f / D_MODEL) - mu * mu;
  float rstd = rsqrtf(var + 1e-5f);
#pragma unroll
  for (int i = 0; i < 4; ++i) {
    int c = t + 256 * i;
    float h = (v[i] - mu) * rstd * g[c] + bb[c];
    out[(size_t)row * D_MODEL + c] = f2b(h);
  }
}

// ---------------- batched 64x64 tile transpose -> bf16 ----------------------
template <typename T>
__global__ __launch_bounds__(256) void transpose_b(
    const T* __restrict__ src, unsigned short* __restrict__ dst,
    int srcStride, int dstStride, long long srcBatch, long long dstBatch) {
  __shared__ unsigned short tile[64][65];
  const T* s = src + (size_t)blockIdx.z * srcBatch;
  unsigned short* d = dst + (size_t)blockIdx.z * dstBatch;
  int n0 = blockIdx.x * 64, k0 = blockIdx.y * 64;
  for (int i = threadIdx.x; i < 4096; i += 256) {
    int k = i >> 6, n = i & 63;
    tile[k][n] = cvt_b(s[(size_t)(k0 + k) * srcStride + n0 + n]);
  }
  __syncthreads();
  for (int i = threadIdx.x; i < 4096; i += 256) {
    int n = i >> 6, k = i & 63;
    d[(size_t)(n0 + n) * dstStride + k0 + k] = tile[k][n];
  }
}

// ---------------- GEMM: C[M,N] = A[M,K] @ Bt[N,K]^T + bias (+res)(+relu) ----
// BMxBN tile, BK=64, 4 waves (2x2); 2-phase dbuf, counted vmcnt, raw barrier.
template <int RES, bool RELU, bool KH, int OUTF, int BM, int BN>
__global__ __launch_bounds__(256) void gemm_bt(
    const unsigned short* __restrict__ A, const unsigned short* __restrict__ Bt,
    const float* __restrict__ bias, const float* __restrict__ res,
    void* __restrict__ out, int M, int N, int K) {
  constexpr int MT = BM / 32;
  constexpr int NT = BN / 32;
  __shared__ __align__(16) unsigned short lsA[2][BM * 64];
  __shared__ __align__(16) unsigned short lsB[2][BN * 64];
  int tid = threadIdx.x;
  int lane = tid & 63, w = tid >> 6, quad = lane >> 4, l16 = lane & 15;
  int bidl = blockIdx.y * (int)gridDim.x + blockIdx.x;
  int swz = xcd_swz(bidl, (int)(gridDim.x * gridDim.y));
  int m0 = (swz / (int)gridDim.x) * BM, n0 = (swz % (int)gridDim.x) * BN;
  int wm = (w >> 1) * (BM / 2), wn = (w & 1) * (BN / 2);
  f4v acc[MT][NT] = {};

  auto stage = [&](int bsel, int ktE) {
#pragma unroll
    for (int i = 0; i < MT; ++i) {
      int cb = w * (BM * 2) + i * 64;
      int ci = cb + lane;
      int row = ci >> 3, c = ci & 7;
      int cs = c ^ (row & 7);
      async16(A + (size_t)(m0 + row) * K + ktE + cs * 8, &lsA[bsel][cb * 8]);
    }
#pragma unroll
    for (int i = 0; i < NT; ++i) {
      int cb = w * (BN * 2) + i * 64;
      int ci = cb + lane;
      int row = ci >> 3, c = ci & 7;
      int cs = c ^ (row & 7);
      async16(Bt + (size_t)(n0 + row) * K + ktE + cs * 8, &lsB[bsel][cb * 8]);
    }
  };

  stage(0, 0);
  int nK = K >> 6;
  for (int kt = 0; kt < nK; ++kt) {
    int b = kt & 1;
    if (kt + 1 < nK) {
      stage(b ^ 1, (kt + 1) << 6);
      if constexpr (MT + NT == 4)      asm volatile("s_waitcnt vmcnt(4)" ::: "memory");
      else if constexpr (MT + NT == 6) asm volatile("s_waitcnt vmcnt(6)" ::: "memory");
      else                             asm volatile("s_waitcnt vmcnt(8)" ::: "memory");
    } else {
      asm volatile("s_waitcnt vmcnt(0)" ::: "memory");
    }
    __builtin_amdgcn_sched_barrier(0);
    __builtin_amdgcn_s_barrier();
    __builtin_amdgcn_sched_barrier(0);
#pragma unroll
    for (int s = 0; s < 2; ++s) {
      s8v af[MT], bf[NT];
#pragma unroll
      for (int t = 0; t < MT; ++t) {
        int am = wm + t * 16 + l16;
        int ac = (s * 4 + quad) ^ (am & 7);
        af[t] = *(const s8v*)(&lsA[b][am * 64 + ac * 8]);
      }
#pragma unroll
      for (int t = 0; t < NT; ++t) {
        int bn = wn + t * 16 + l16;
        int bc = (s * 4 + quad) ^ (bn & 7);
        bf[t] = *(const s8v*)(&lsB[b][bn * 64 + bc * 8]);
      }
#pragma unroll
      for (int ti = 0; ti < MT; ++ti)
#pragma unroll
        for (int tj = 0; tj < NT; ++tj)
          acc[ti][tj] = __builtin_amdgcn_mfma_f32_16x16x32_bf16(
              af[ti], bf[tj], acc[ti][tj], 0, 0, 0);
    }
    asm volatile("s_waitcnt lgkmcnt(0)" ::: "memory");
    __builtin_amdgcn_sched_barrier(0);
    __builtin_amdgcn_s_barrier();
    __builtin_amdgcn_sched_barrier(0);
  }
#pragma unroll
  for (int tj = 0; tj < NT; ++tj) {
    int col = n0 + wn + tj * 16 + l16;
    float bv = bias[col];
#pragma unroll
    for (int ti = 0; ti < MT; ++ti) {
#pragma unroll
      for (int r = 0; r < 4; ++r) {
        int rowg = m0 + wm + ti * 16 + quad * 4 + r;
        float vv = acc[ti][tj][r] + bv;
        if (KH) vv *= KH_SCALE;
        if (RES == 2) vv += res[(size_t)rowg * N + col];
        if (RELU) vv = fmaxf(vv, 0.f);
        size_t oidx;
        if (KH) {
          int b2 = rowg >> 11, l = rowg & 2047, h = col >> 6, d = col & 63;
          oidx = (((size_t)(b2 * NH + h)) * SEQ + l) * DH + d;
        } else {
          oidx = (size_t)rowg * N + col;
        }
        if (OUTF == 0) ((unsigned short*)out)[oidx] = f2b(vv);
        else           ((float*)out)[oidx] = vv;
      }
    }
  }
}

// ---------------- 256x256 8-phase GEMM (T3+T4+T5), bf16 out + bias (+relu) --
// 8 waves (2Mx4N), per-wave 128x64, BK=64. LDS: [parity][half] 128x64 halves,
// A-half h = quadrant rows {wr*128 + h*64 ..+64}; B-half h = cols
// {wc*64 + h*32 ..+32}. Quadrant order 00,10,01,11; one half-tile staged per
// phase (order A1 B1 | B0 A0 | A1 B1 | B0 A0); counted vmcnt(4) at ph4/ph8
// only (2 halves stay in flight; 3 ahead at issue). Derivation in R14 notes.
__global__ __launch_bounds__(512, 2) void gemm256(
    const unsigned short* __restrict__ A, const unsigned short* __restrict__ Bt,
    const float* __restrict__ bias, unsigned short* __restrict__ out,
    bool relu, int M, int N, int K) {
  __shared__ __align__(16) unsigned short lsA[2][2][128 * 64];
  __shared__ __align__(16) unsigned short lsB[2][2][128 * 64];
  int tid = threadIdx.x;
  int lane = tid & 63, w = tid >> 6, quad = lane >> 4, l16 = lane & 15;
  int wr = w >> 2, wc = w & 3;
  int bidl = blockIdx.y * (int)gridDim.x + blockIdx.x;
  int swz = xcd_swz(bidl, (int)(gridDim.x * gridDim.y));
  int m0 = (swz / (int)gridDim.x) * 256, n0 = (swz % (int)gridDim.x) * 256;
  f4v acc[8][4] = {};

  // stage one 128x64 half-tile; local row r -> global per half-mapping
  auto stageA = [&](int par, int h, int kt) {
#pragma unroll
    for (int i = 0; i < 2; ++i) {
      int cb = w * 128 + i * 64;
      int ci = cb + lane;
      int r = ci >> 3, c = ci & 7;
      int cs = c ^ (r & 7);
      int grow = ((r >> 6) << 7) + h * 64 + (r & 63);  // quadrant-row split
      async16(A + (size_t)(m0 + grow) * K + kt * 64 + cs * 8,
              &lsA[par][h][cb * 8]);
    }
  };
  auto stageB = [&](int par, int h, int kt) {
#pragma unroll
    for (int i = 0; i < 2; ++i) {
      int cb = w * 128 + i * 64;
      int ci = cb + lane;
      int r = ci >> 3, c = ci & 7;
      int cs = c ^ (r & 7);
      int gn = ((r >> 5) << 6) + h * 32 + (r & 31);    // quadrant-col split
      async16(Bt + (size_t)(n0 + gn) * K + kt * 64 + cs * 8,
              &lsB[par][h][cb * 8]);
    }
  };

// one phase: ds-read quadrant operands, issue stage, barrier, 16 MFMA
// (setprio-wrapped), optional counted vmcnt, barrier. PAR/MH/NH literal ->
// static acc indexing (rule #20).
#define PHASE(PAR, MH, NH, STAGE_STMT, VMN)                                    \
  {                                                                            \
    s8v af[4][2], bf[2][2];                                                    \
    _Pragma("unroll") for (int tm = 0; tm < 4; ++tm) {                         \
      int lr = wr * 64 + tm * 16 + l16;                                        \
      _Pragma("unroll") for (int s = 0; s < 2; ++s) {                          \
        int ac = (s * 4 + quad) ^ (lr & 7);                                    \
        af[tm][s] = *(const s8v*)(&lsA[PAR][MH][lr * 64 + ac * 8]);            \
      }                                                                        \
    }                                                                          \
    _Pragma("unroll") for (int tn = 0; tn < 2; ++tn) {                         \
      int rb = wc * 32 + tn * 16 + l16;                                        \
      _Pragma("unroll") for (int s = 0; s < 2; ++s) {                          \
        int bc = (s * 4 + quad) ^ (rb & 7);                                    \
        bf[tn][s] = *(const s8v*)(&lsB[PAR][NH][rb * 64 + bc * 8]);            \
      }                                                                        \
    }                                                                          \
    STAGE_STMT;                                                                \
    __builtin_amdgcn_sched_barrier(0);                                         \
    __builtin_amdgcn_s_barrier();                                              \
    __builtin_amdgcn_sched_barrier(0);                                         \
    __builtin_amdgcn_s_setprio(1);                                             \
    _Pragma("unroll") for (int s = 0; s < 2; ++s)                              \
      _Pragma("unroll") for (int tm = 0; tm < 4; ++tm)                         \
        _Pragma("unroll") for (int tn = 0; tn < 2; ++tn)                       \
          acc[MH * 4 + tm][NH * 2 + tn] =                                      \
              __builtin_amdgcn_mfma_f32_16x16x32_bf16(                         \
                  af[tm][s], bf[tn][s], acc[MH * 4 + tm][NH * 2 + tn], 0, 0, 0);\
    __builtin_amdgcn_s_setprio(0);                                             \
    __builtin_amdgcn_sched_barrier(0);                                         \
    if (VMN == 4) { asm volatile("s_waitcnt vmcnt(4)" ::: "memory"); }         \
    else if (VMN == 0) { asm volatile("s_waitcnt vmcnt(0)" ::: "memory"); }    \
    __builtin_amdgcn_sched_barrier(0);                                         \
    __builtin_amdgcn_s_barrier();                                              \
    __builtin_amdgcn_sched_barrier(0);                                         \
  }

  int nT = K >> 6;  // assumes nT even, >= 4
  // prologue: issue order A0(0) B0(0) A1(0) B1(0) B0(1) A0(1); keep last 2
  stageA(0, 0, 0); stageB(0, 0, 0); stageA(0, 1, 0); stageB(0, 1, 0);
  stageB(1, 0, 1); stageA(1, 0, 1);
  asm volatile("s_waitcnt vmcnt(4)" ::: "memory");
  __builtin_amdgcn_sched_barrier(0);
  __builtin_amdgcn_s_barrier();
  __builtin_amdgcn_sched_barrier(0);

  for (int t = 0; t < nT; t += 2) {
    bool s2 = (t + 2) < nT, s3 = (t + 3) < nT;
    PHASE(0, 0, 0, { stageA(1, 1, t + 1); }, -1)                 // ph1
    PHASE(0, 1, 0, { stageB(1, 1, t + 1); }, -1)                 // ph2
    PHASE(0, 0, 1, { if (s2) stageB(0, 0, t + 2); }, -1)         // ph3
    PHASE(0, 1, 1, { if (s2) stageA(0, 0, t + 2); }, (s2 ? 4 : 0)) // ph4
    PHASE(1, 0, 0, { if (s2) stageA(0, 1, t + 2); }, -1)         // ph5
    PHASE(1, 1, 0, { if (s2) stageB(0, 1, t + 2); }, -1)         // ph6
    PHASE(1, 0, 1, { if (s3) stageB(1, 0, t + 3); }, -1)         // ph7
    PHASE(1, 1, 1, { if (s3) stageA(1, 0, t + 3); }, (s3 ? 4 : 0)) // ph8
  }
#undef PHASE

  // epilogue: C/D layout col=lane&15, row=quad*4+r
#pragma unroll
  for (int mi = 0; mi < 8; ++mi) {
    int mh = mi >> 2, tm = mi & 3;
#pragma unroll
    for (int nj = 0; nj < 4; ++nj) {
      int nh = nj >> 1, tn = nj & 1;
      int col = n0 + wc * 64 + nh * 32 + tn * 16 + l16;
      float bv = bias[col];
#pragma unroll
      for (int r = 0; r < 4; ++r) {
        int rowg = m0 + wr * 128 + mh * 64 + tm * 16 + quad * 4 + r;
        float vv = acc[mi][nj][r] + bv;
        if (relu) vv = fmaxf(vv, 0.f);
        out[(size_t)rowg * N + col] = f2b(vv);
      }
    }
  }
}

// ---------------- proj GEMM with fused attention-combine A-staging ----------
__global__ __launch_bounds__(256) void gemm_proj(
    const unsigned short* __restrict__ Opart, const float* __restrict__ lpart,
    const unsigned short* __restrict__ Bt, const float* __restrict__ bias,
    const float* __restrict__ res, float* __restrict__ out, int M, int N, int K) {
  __shared__ __align__(16) unsigned short lsA[2][64 * 64];
  __shared__ __align__(16) unsigned short lsB[2][64 * 64];
  int tid = threadIdx.x;
  int lane = tid & 63, w = tid >> 6, quad = lane >> 4, l16 = lane & 15;
  int bidl = blockIdx.y * (int)gridDim.x + blockIdx.x;
  int swz = xcd_swz(bidl, (int)(gridDim.x * gridDim.y));
  int m0 = (swz / (int)gridDim.x) * 64, n0 = (swz % (int)gridDim.x) * 64;
  int wm = (w >> 1) * 32, wn = (w & 1) * 32;
  f4v acc[2][2] = {};

  int ci_[2], csA[2], mA[2], b2A[2], lA[2];
#pragma unroll
  for (int i = 0; i < 2; ++i) {
    int cb = w * 128 + i * 64;
    int ci = cb + lane;
    int row = ci >> 3, c = ci & 7;
    ci_[i] = ci; csA[i] = c ^ (row & 7);
    mA[i] = m0 + row; b2A[i] = mA[i] >> 11; lA[i] = mA[i] & 2047;
  }
  s8v o0r[2], o1r[2];
  float lsr0[2], lsr1[2];
  auto issueA = [&](int kt) {
#pragma unroll
    for (int i = 0; i < 2; ++i) {
      const unsigned short* pa =
          Opart + (size_t)mA[i] * D_MODEL + kt * 64 + csA[i] * 8;
      o0r[i] = *(const s8v*)pa;
      o1r[i] = *(const s8v*)(pa + (size_t)MROWS * D_MODEL);
      size_t lidx = ((size_t)b2A[i] * NH + kt) * SEQ + lA[i];
      lsr0[i] = lpart[lidx];
      lsr1[i] = lpart[(size_t)BATCH * NH * SEQ + lidx];
    }
  };
  auto issueB = [&](int bsel, int ktE) {
#pragma unroll
    for (int i = 0; i < 2; ++i) {
      int cb = w * 128 + i * 64;
      int ci = cb + lane;
      int row = ci >> 3, c = ci & 7;
      int cs = c ^ (row & 7);
      async16(Bt + (size_t)(n0 + row) * K + ktE + cs * 8, &lsB[bsel][cb * 8]);
    }
  };
  auto combineWrite = [&](int bsel) {
#pragma unroll
    for (int i = 0; i < 2; ++i) {
      float inv = KH_ISCALE / (lsr0[i] + lsr1[i]);
      float f[8];
#pragma unroll
      for (int j = 0; j < 8; ++j)
        f[j] = (b2f((unsigned short)o0r[i][j]) +
                b2f((unsigned short)o1r[i][j])) * inv;
      s4v lo = cvt4(f[0], f[1], f[2], f[3]);
      s4v hi = cvt4(f[4], f[5], f[6], f[7]);
      s8v vv = {lo[0], lo[1], lo[2], lo[3], hi[0], hi[1], hi[2], hi[3]};
      *(s8v*)(&lsA[bsel][ci_[i] * 8]) = vv;
    }
  };

  issueA(0); issueB(0, 0);
  __builtin_amdgcn_sched_barrier(0);
  asm volatile("s_waitcnt vmcnt(2)" ::: "memory");
  __builtin_amdgcn_sched_barrier(0);
  combineWrite(0);
  asm volatile("s_waitcnt lgkmcnt(0)" ::: "memory");
  __builtin_amdgcn_sched_barrier(0);

  int nK = K >> 6;
  for (int kt = 0; kt < nK; ++kt) {
    int b = kt & 1;
    if (kt + 1 < nK) {
      issueA(kt + 1); issueB(b ^ 1, (kt + 1) << 6);
      __builtin_amdgcn_sched_barrier(0);
      asm volatile("s_waitcnt vmcnt(10)" ::: "memory");
    } else {
      __builtin_amdgcn_sched_barrier(0);
      asm volatile("s_waitcnt vmcnt(0)" ::: "memory");
    }
    __builtin_amdgcn_sched_barrier(0);
    __builtin_amdgcn_s_barrier();
    __builtin_amdgcn_sched_barrier(0);
#pragma unroll
    for (int s = 0; s < 2; ++s) {
      s8v af[2], bf[2];
#pragma unroll
      for (int t = 0; t < 2; ++t) {
        int am = wm + t * 16 + l16;
        int ac = (s * 4 + quad) ^ (am & 7);
        af[t] = *(const s8v*)(&lsA[b][am * 64 + ac * 8]);
      }
#pragma unroll
      for (int t = 0; t < 2; ++t) {
        int bn = wn + t * 16 + l16;
        int bc = (s * 4 + quad) ^ (bn & 7);
        bf[t] = *(const s8v*)(&lsB[b][bn * 64 + bc * 8]);
      }
#pragma unroll
      for (int ti = 0; ti < 2; ++ti)
#pragma unroll
        for (int tj = 0; tj < 2; ++tj)
          acc[ti][tj] = __builtin_amdgcn_mfma_f32_16x16x32_bf16(
              af[ti], bf[tj], acc[ti][tj], 0, 0, 0);
    }
    if (kt + 1 < nK) {
      __builtin_amdgcn_sched_barrier(0);
      asm volatile("s_waitcnt vmcnt(2)" ::: "memory");
      __builtin_amdgcn_sched_barrier(0);
      combineWrite(b ^ 1);
    }
    asm volatile("s_waitcnt lgkmcnt(0)" ::: "memory");
    __builtin_amdgcn_sched_barrier(0);
    __builtin_amdgcn_s_barrier();
    __builtin_amdgcn_sched_barrier(0);
  }
#pragma unroll
  for (int tj = 0; tj < 2; ++tj) {
    int col = n0 + wn + tj * 16 + l16;
    float bv = bias[col];
#pragma unroll
    for (int ti = 0; ti < 2; ++ti) {
#pragma unroll
      for (int r = 0; r < 4; ++r) {
        int rowg = m0 + wm + ti * 16 + quad * 4 + r;
        float vv = acc[ti][tj][r] + bv + res[(size_t)rowg * N + col];
        out[(size_t)rowg * N + col] = vv;
      }
    }
  }
}

// ---------------- fused flash attention, register-P, XCD-local --------------
__global__ __launch_bounds__(256) void flash_k(
    const unsigned short* __restrict__ kh, const unsigned short* __restrict__ khT,
    unsigned short* __restrict__ Opart, float* __restrict__ lpart) {
  __shared__ __align__(16) unsigned short lsK[128 * 64];   // [key][d], 8-chunk rows
  __shared__ __align__(16) unsigned short lsKT[64 * 128];  // [d][key], 16-chunk rows
  int tid = threadIdx.x;
  int lane = tid & 63, w = tid >> 6, quad = lane >> 4, l16 = lane & 15;
  int split = blockIdx.x, bh = blockIdx.y, qb = blockIdx.z;
  const unsigned short* khB = kh + (size_t)bh * SEQ * DH;
  const unsigned short* khTB = khT + (size_t)bh * DH * SEQ;
  unsigned short* Op = Opart + (size_t)split * MROWS * D_MODEL;
  float* lp = lpart + (size_t)split * BATCH * NH * SEQ;
  s8v aQ[2][2];
#pragma unroll
  for (int g = 0; g < 2; ++g) {
    int q = qb * 128 + w * 32 + g * 16 + l16;
#pragma unroll
    for (int s = 0; s < 2; ++s)
      aQ[g][s] = *(const s8v*)(khB + (size_t)q * DH + s * 32 + quad * 8);
  }
  const s4v vone = {(short)0x3F80, (short)0x3F80, (short)0x3F80, (short)0x3F80};
  f4v accO[2][4] = {};
  f4v accL[2] = {};

  for (int kt8 = 0; kt8 < 8; ++kt8) {
    int key0 = split * 1024 + kt8 * 128;
#pragma unroll
    for (int i = 0; i < 4; ++i) {
      int cb = w * 256 + i * 64;
      int ci = cb + lane;
      int row = ci >> 3, c = ci & 7;
      int cs = c ^ (row & 7);
      async16(khB + (size_t)(key0 + row) * DH + cs * 8, &lsK[cb * 8]);
    }
#pragma unroll
    for (int i = 0; i < 4; ++i) {
      int cb = w * 256 + i * 64;
      int ci = cb + lane;
      int row = ci >> 4, c = ci & 15;
      int cs = c ^ (row & 15);
      async16(khTB + (size_t)row * SEQ + key0 + cs * 8, &lsKT[cb * 8]);
    }
    __builtin_amdgcn_s_waitcnt(0x0f70);  // vmcnt(0)
    __syncthreads();
#pragma unroll
    for (int half = 0; half < 2; ++half) {
      f4v accST[2][4] = {};
#pragma unroll
      for (int s = 0; s < 2; ++s) {
#pragma unroll
        for (int tj = 0; tj < 4; ++tj) {
          int key = half * 64 + tj * 16 + l16;
          int c = (s * 4 + quad) ^ (key & 7);
          s8v kf = *(const s8v*)(&lsK[key * 64 + c * 8]);
#pragma unroll
          for (int g = 0; g < 2; ++g)
            accST[g][tj] = __builtin_amdgcn_mfma_f32_16x16x32_bf16(
                kf, aQ[g][s], accST[g][tj], 0, 0, 0);
        }
      }
#pragma unroll
      for (int tj = 0; tj < 4; ++tj) {
        s4v pf[2];
#pragma unroll
        for (int g = 0; g < 2; ++g) {
          float p0 = xp2(accST[g][tj][0]);
          float p1 = xp2(accST[g][tj][1]);
          float p2 = xp2(accST[g][tj][2]);
          float p3 = xp2(accST[g][tj][3]);
          pf[g] = cvt4(p0, p1, p2, p3);
          accL[g] = mfma16(pf[g], vone, accL[g]);
        }
#pragma unroll
        for (int db = 0; db < 4; ++db) {
          int d = db * 16 + l16;
          int ch = (half * 8 + tj * 2 + (quad >> 1)) ^ (d & 15);
          s4v vf = *(const s4v*)(&lsKT[d * 128 + ch * 8 + (quad & 1) * 4]);
#pragma unroll
          for (int g = 0; g < 2; ++g)
            accO[g][db] = mfma16(pf[g], vf, accO[g][db]);
        }
      }
    }
    __syncthreads();
  }
  int b = bh >> 4, h = bh & 15;
#pragma unroll
  for (int g = 0; g < 2; ++g) {
    if (l16 == 0) {
#pragma unroll
      for (int r = 0; r < 4; ++r) {
        int q = qb * 128 + w * 32 + g * 16 + quad * 4 + r;
        lp[(size_t)bh * SEQ + q] = accL[g][r];
      }
    }
#pragma unroll
    for (int r = 0; r < 4; ++r) {
      int l = qb * 128 + w * 32 + g * 16 + quad * 4 + r;
#pragma unroll
      for (int db = 0; db < 4; ++db) {
        int d = db * 16 + l16;
        Op[((size_t)(b * SEQ + l)) * D_MODEL + h * DH + d] = f2b(accO[g][db][r]);
      }
    }
  }
}

// ---------------------------------------------------------------------------
extern "C" void kernel_launch(void* const* d_in, const int* in_sizes, int n_in,
                              void* d_out, int out_size, void* d_ws, size_t ws_size,
                              hipStream_t stream) {
  (void)in_sizes; (void)n_in; (void)out_size;
  const float* x      = (const float*)d_in[0];
  const float* w_attn = (const float*)d_in[1];
  const float* b_attn = (const float*)d_in[2];
  const float* w_proj = (const float*)d_in[3];
  const float* b_proj = (const float*)d_in[4];
  const float* ln1_g  = (const float*)d_in[5];
  const float* ln1_b  = (const float*)d_in[6];
  const float* ln2_g  = (const float*)d_in[7];
  const float* ln2_b  = (const float*)d_in[8];
  const float* w_fc1  = (const float*)d_in[9];
  const float* b_fc1  = (const float*)d_in[10];
  const float* w_fc2  = (const float*)d_in[11];
  const float* b_fc2  = (const float*)d_in[12];

  char* ws = (char*)d_ws;
  unsigned short* Opart = (unsigned short*)ws;                         // [0,16M)
  unsigned short* kh    = (unsigned short*)(ws + (size_t)(16u << 20)); // [16,24)
  unsigned short* khT   = (unsigned short*)(ws + (size_t)(24u << 20)); // [24,32)
  float*          x1    = (float*)(ws + (size_t)(32u << 20));          // [32,48)
  unsigned short* hbuf  = (unsigned short*)(ws + (size_t)(48u << 20)); // [48,56)
  float*          lpart = (float*)(ws + (size_t)(48u << 20));  // h1 dead by flash
  float* outf = (float*)d_out;
  bool big_ws = ws_size >= ((size_t)72u << 20);

  unsigned short* wTk;
  unsigned short* wTp;
  unsigned short* wTf1;
  unsigned short* wTf2;
  unsigned short* fc1o;
  if (big_ws) {
    wTk  = (unsigned short*)(ws + (size_t)(56u << 20));
    wTp  = wTk;
    wTf1 = wTk;
    wTf2 = (unsigned short*)(ws + (size_t)(64u << 20));
    fc1o = (unsigned short*)ws;                            // [0,32): Op/kh/khT dead
  } else {
    wTk  = (unsigned short*)ws;
    wTp  = kh;
    wTf1 = (unsigned short*)ws;
    wTf2 = (unsigned short*)(ws + (size_t)(8u << 20));
    fc1o = kh;
  }

  dim3 blk(256);
  // 1. h1 = LN1(x)
  hipLaunchKernelGGL(ln_kernel, dim3(MROWS), blk, 0, stream, x, ln1_g, ln1_b, hbuf);
  // 2. wTk = (w_attn[:, 1024:2048])^T
  hipLaunchKernelGGL(transpose_b<float>, dim3(16, 16, 1), blk, 0, stream,
                     w_attn + 1024, wTk, 3 * D_MODEL, D_MODEL, 0LL, 0LL);
  // 3. kh[b,h,l,d] = (h1 @ w_k + b_k) * KH_SCALE
  hipLaunchKernelGGL((gemm_bt<0, false, true, 0, 64, 64>), dim3(16, 64), blk, 0,
                     stream, hbuf, wTk, b_attn + 1024, nullptr, (void*)kh,
                     MROWS, D_MODEL, D_MODEL);
  // 4. khT[b,h,d,l] = transpose(kh) per head
  hipLaunchKernelGGL(transpose_b<unsigned short>, dim3(1, 32, 32), blk, 0, stream,
                     kh, khT, DH, SEQ, (long long)(SEQ * DH), (long long)(DH * SEQ));
  // 5. flash -> bf16 unnormalized partials + l partials
  hipLaunchKernelGGL(flash_k, dim3(2, 32, SEQ / 128), blk, 0, stream,
                     kh, khT, Opart, lpart);
  // 6. wTp = w_proj^T ; x1 = combine(Opart,lpart) @ w_proj + b + x  (fused)
  hipLaunchKernelGGL(transpose_b<float>, dim3(16, 16, 1), blk, 0, stream,
                     w_proj, wTp, D_MODEL, D_MODEL, 0LL, 0LL);
  hipLaunchKernelGGL(gemm_proj, dim3(16, 64), blk, 0, stream,
                     Opart, lpart, wTp, b_proj, x, x1,
                     MROWS, D_MODEL, D_MODEL);
  // 7. h2 = LN2(x1)
  hipLaunchKernelGGL(ln_kernel, dim3(MROWS), blk, 0, stream, x1, ln2_g, ln2_b, hbuf);
  // 8. wTf1 = w_fc1^T ; wTf2 = w_fc2^T
  hipLaunchKernelGGL(transpose_b<float>, dim3(64, 16, 1), blk, 0, stream,
                     w_fc1, wTf1, 4 * D_MODEL, D_MODEL, 0LL, 0LL);
  hipLaunchKernelGGL(transpose_b<float>, dim3(16, 64, 1), blk, 0, stream,
                     w_fc2, wTf2, D_MODEL, 4 * D_MODEL, 0LL, 0LL);
  // 9/10. FFN: FC1 8-phase 256^2 (256 blocks = 1/CU); FC2 BM=64 (1024 blocks)
  if (big_ws) {
    hipLaunchKernelGGL(gemm256, dim3(16, 16), dim3(512), 0, stream,
                       hbuf, wTf1, b_fc1, fc1o, true,
                       MROWS, 4 * D_MODEL, D_MODEL);
    hipLaunchKernelGGL((gemm_bt<2, false, false, 1, 64, 64>), dim3(16, 64), blk, 0,
                       stream, fc1o, wTf2, b_fc2, x1, (void*)outf,
                       MROWS, D_MODEL, 4 * D_MODEL);
  } else {
    for (int c = 0; c < 2; ++c) {
      const unsigned short* h2c = hbuf + (size_t)c * 2048 * D_MODEL;
      const float* x1c = x1 + (size_t)c * 2048 * D_MODEL;
      float* outc = outf + (size_t)c * 2048 * D_MODEL;
      hipLaunchKernelGGL((gemm_bt<0, true, false, 0, 128, 64>), dim3(64, 16), blk, 0,
                         stream, h2c, wTf1, b_fc1, nullptr, (void*)fc1o,
                         2048, 4 * D_MODEL, D_MODEL);
      hipLaunchKernelGGL((gemm_bt<2, false, false, 1, 64, 64>), dim3(16, 32), blk, 0,
                         stream, fc1o, wTf2, b_fc2, x1c, (void*)outc,
                         2048, D_MODEL, 4 * D_MODEL);
    }
  }
}

// Round 7
// 321.069 us; speedup vs baseline: 1.0638x; 1.0323x over previous
//
#include <hip/hip_runtime.h>

// ---------------------------------------------------------------------------
// Transformer block on MI355X. fp32 I/O (per reference), bf16 MFMA internals,
// fp32 accumulation/residuals.
// R16 == R15 resubmit (R15 bench died with "container failed twice" = infra;
// audit re-verified tr-read lane model vs m156, accL K=32 packing, LDS
// bounds, barrier uniformity -- no hang/fault path exists in-kernel).
// R15: flash restructure. R14 post-mortem: flash_k is the profile head
// (57.3us, MfmaUtil 41 + VALU 44 = ~issue-bound, 4.2M LDS conflicts, 8
// vmcnt(0) drains). Changes:
//  (a) lsK subtiled [4 dblk][128 key][16 d]; PV B-fragments read with
//      ds_read_b64_tr_b16 (T10): per-lane addr quad*128B+l16*8B + const
//      offset == V[KB+quad*4+j][db*16+l16] per m156/m162 lane model.
//      khT buffer + its transpose kernel + its staging DELETED. kf (QK^T)
//      reads in this layout are natural stride-32B = exact-min bank cycles
//      (no XOR swizzle anywhere in flash).
//  (b) lsK double-buffered (2x16KB), counted vmcnt(4) steady state, raw
//      barriers; per-tj tr-reads fenced with lgkmcnt(0)+sched_barrier
//      (rule #18: compiler won't order MFMAs vs inline-asm ds reads).
//  (c) accL via K=32 mfma on tj-pairs (B=ones makes k-position irrelevant
//      -> in-lane concat, no cross-lane): 128 mfma16 -> 64 mfma32.
// R14 kept: 8-phase 256^2 gemm256 for FC1 (T3+T4+T5). R13: XCD-chunked
// swizzle, fused combine-proj. R12: BM=64 N=1024 GEMMs. R11: 2-phase dbuf.
// R10: kexp in kh, cvt_pk, bare exp2. R9: XCD-local flash grid.
// ws layout (56MB min, 72MB preferred):
//   [0,16M)  Opart | big: fc1o [0,32M) after proj
//   [16,24M) kh    | fallback: fc1o [16,32M)
//   [24,32M) (free; was khT)
//   [32,48M) x1    [48,56M) hbuf + lpart during flash
//   [56,64M) wT1 (big), [64,72M) wT2 (big)
// ---------------------------------------------------------------------------

typedef __attribute__((ext_vector_type(8))) short s8v;  // 8 bf16 raw
typedef __attribute__((ext_vector_type(4))) short s4v;  // 4 bf16 raw
typedef __attribute__((ext_vector_type(4))) float f4v;  // mfma accumulator

#define D_MODEL 1024
#define SEQ 2048
#define BATCH 2
#define NH 16
#define DH 64
#define MROWS (BATCH * SEQ)

#define KH_SCALE 0.42466088f
#define KH_ISCALE 2.3548200f

__device__ __forceinline__ float b2f(unsigned short u) {
  union { unsigned int i; float f; } v; v.i = ((unsigned int)u) << 16; return v.f;
}
__device__ __forceinline__ unsigned short f2b(float f) {
  unsigned int i = __builtin_bit_cast(unsigned int, f);
  unsigned int r = (i + 0x7fffu + ((i >> 16) & 1u)) >> 16;  // RNE
  return (unsigned short)r;
}
// async global->LDS, 16B/lane; dest = wave-uniform base + lane*16 (m104/m108)
__device__ __forceinline__ void async16(const void* g, void* l) {
  __builtin_amdgcn_global_load_lds(
      (const __attribute__((address_space(1))) unsigned int*)g,
      (__attribute__((address_space(3))) unsigned int*)l, 16, 0, 0);
}
__device__ __forceinline__ unsigned short cvt_b(float f) { return f2b(f); }
__device__ __forceinline__ unsigned short cvt_b(unsigned short u) { return u; }

__device__ __forceinline__ float xp2(float x) {
#if __has_builtin(__builtin_amdgcn_exp2f)
  return __builtin_amdgcn_exp2f(x);
#else
  return exp2f(x);
#endif
}

// 4x f32 -> packed bf16 s4v via v_cvt_pk_bf16_f32 (RNE, 2 instructions).
__device__ __forceinline__ s4v cvt4(float a, float b, float c, float d) {
  unsigned int lo, hi;
  asm("v_cvt_pk_bf16_f32 %0, %1, %2" : "=v"(lo) : "v"(a), "v"(b));
  asm("v_cvt_pk_bf16_f32 %0, %1, %2" : "=v"(hi) : "v"(c), "v"(d));
  union { unsigned long long u; s4v v; } u;
  u.u = ((unsigned long long)hi << 32) | (unsigned long long)lo;
  return u.v;
}

#if __has_builtin(__builtin_amdgcn_mfma_f32_16x16x16_bf16)
__device__ __forceinline__ f4v mfma16(s4v a, s4v b, f4v c) {
  return __builtin_amdgcn_mfma_f32_16x16x16_bf16(a, b, c, 0, 0, 0);
}
#elif __has_builtin(__builtin_amdgcn_mfma_f32_16x16x16bf16_1k)
__device__ __forceinline__ f4v mfma16(s4v a, s4v b, f4v c) {
  return __builtin_amdgcn_mfma_f32_16x16x16bf16_1k(a, b, c, 0, 0, 0);
}
#else
__device__ __forceinline__ f4v mfma16(s4v a, s4v b, f4v c) {
  s8v aa = {a[0], a[1], a[2], a[3], 0, 0, 0, 0};
  s8v bb = {b[0], b[1], b[2], b[3], 0, 0, 0, 0};
  return __builtin_amdgcn_mfma_f32_16x16x32_bf16(aa, bb, c, 0, 0, 0);
}
#endif

// LDS transpose-read: supply the natural per-lane ds_read_b64 address
// (base + lane*8B); each 16-lane group's 128B region is delivered
// column-major: lane l gets column (l&15) of its 4x16 bf16 tile (m156/m162).
typedef __attribute__((address_space(3))) const unsigned short* lds_cp;
__device__ __forceinline__ s4v tr16(lds_cp p) {
  unsigned long long d;
  asm volatile("ds_read_b64_tr_b16 %0, %1" : "=v"(d) : "v"(p));
  return __builtin_bit_cast(s4v, d);
}

// XCD-chunked logical block id (T1); bijective only when nwg%8==0.
__device__ __forceinline__ int xcd_swz(int bidl, int nwg) {
  return (nwg & 7) ? bidl : ((bidl & 7) * (nwg >> 3) + (bidl >> 3));
}

// ---------------- LayerNorm: fp32 in -> bf16 out, one block per row ---------
__global__ __launch_bounds__(256) void ln_kernel(
    const float* __restrict__ x, const float* __restrict__ g,
    const float* __restrict__ bb, unsigned short* __restrict__ out) {
  int row = blockIdx.x;
  int t = threadIdx.x;
  const float* xr = x + (size_t)row * D_MODEL;
  float v[4];
  float s = 0.f, s2 = 0.f;
#pragma unroll
  for (int i = 0; i < 4; ++i) {
    float f = xr[t + 256 * i];
    v[i] = f; s += f; s2 += f * f;
  }
#pragma unroll
  for (int off = 1; off < 64; off <<= 1) {
    s += __shfl_xor(s, off, 64);
    s2 += __shfl_xor(s2, off, 64);
  }
  __shared__ float red[8];
  if ((t & 63) == 0) { red[t >> 6] = s; red[4 + (t >> 6)] = s2; }
  __syncthreads();
  s = red[0] + red[1] + red[2] + red[3];
  s2 = red[4] + red[5] + red[6] + red[7];
  float mu = s * (1.f / D_MODEL);
  float var = s2 * (1.f / D_MODEL) - mu * mu;
  float rstd = rsqrtf(var + 1e-5f);
#pragma unroll
  for (int i = 0; i < 4; ++i) {
    int c = t + 256 * i;
    float h = (v[i] - mu) * rstd * g[c] + bb[c];
    out[(size_t)row * D_MODEL + c] = f2b(h);
  }
}

// ---------------- batched 64x64 tile transpose -> bf16 ----------------------
template <typename T>
__global__ __launch_bounds__(256) void transpose_b(
    const T* __restrict__ src, unsigned short* __restrict__ dst,
    int srcStride, int dstStride, long long srcBatch, long long dstBatch) {
  __shared__ unsigned short tile[64][65];
  const T* s = src + (size_t)blockIdx.z * srcBatch;
  unsigned short* d = dst + (size_t)blockIdx.z * dstBatch;
  int n0 = blockIdx.x * 64, k0 = blockIdx.y * 64;
  for (int i = threadIdx.x; i < 4096; i += 256) {
    int k = i >> 6, n = i & 63;
    tile[k][n] = cvt_b(s[(size_t)(k0 + k) * srcStride + n0 + n]);
  }
  __syncthreads();
  for (int i = threadIdx.x; i < 4096; i += 256) {
    int n = i >> 6, k = i & 63;
    d[(size_t)(n0 + n) * dstStride + k0 + k] = tile[k][n];
  }
}

// ---------------- GEMM: C[M,N] = A[M,K] @ Bt[N,K]^T + bias (+res)(+relu) ----
// BMxBN tile, BK=64, 4 waves (2x2); 2-phase dbuf, counted vmcnt, raw barrier.
template <int RES, bool RELU, bool KH, int OUTF, int BM, int BN>
__global__ __launch_bounds__(256) void gemm_bt(
    const unsigned short* __restrict__ A, const unsigned short* __restrict__ Bt,
    const float* __restrict__ bias, const float* __restrict__ res,
    void* __restrict__ out, int M, int N, int K) {
  constexpr int MT = BM / 32;
  constexpr int NT = BN / 32;
  __shared__ __align__(16) unsigned short lsA[2][BM * 64];
  __shared__ __align__(16) unsigned short lsB[2][BN * 64];
  int tid = threadIdx.x;
  int lane = tid & 63, w = tid >> 6, quad = lane >> 4, l16 = lane & 15;
  int bidl = blockIdx.y * (int)gridDim.x + blockIdx.x;
  int swz = xcd_swz(bidl, (int)(gridDim.x * gridDim.y));
  int m0 = (swz / (int)gridDim.x) * BM, n0 = (swz % (int)gridDim.x) * BN;
  int wm = (w >> 1) * (BM / 2), wn = (w & 1) * (BN / 2);
  f4v acc[MT][NT] = {};

  auto stage = [&](int bsel, int ktE) {
#pragma unroll
    for (int i = 0; i < MT; ++i) {
      int cb = w * (BM * 2) + i * 64;
      int ci = cb + lane;
      int row = ci >> 3, c = ci & 7;
      int cs = c ^ (row & 7);
      async16(A + (size_t)(m0 + row) * K + ktE + cs * 8, &lsA[bsel][cb * 8]);
    }
#pragma unroll
    for (int i = 0; i < NT; ++i) {
      int cb = w * (BN * 2) + i * 64;
      int ci = cb + lane;
      int row = ci >> 3, c = ci & 7;
      int cs = c ^ (row & 7);
      async16(Bt + (size_t)(n0 + row) * K + ktE + cs * 8, &lsB[bsel][cb * 8]);
    }
  };

  stage(0, 0);
  int nK = K >> 6;
  for (int kt = 0; kt < nK; ++kt) {
    int b = kt & 1;
    if (kt + 1 < nK) {
      stage(b ^ 1, (kt + 1) << 6);
      if constexpr (MT + NT == 4)      asm volatile("s_waitcnt vmcnt(4)" ::: "memory");
      else if constexpr (MT + NT == 6) asm volatile("s_waitcnt vmcnt(6)" ::: "memory");
      else                             asm volatile("s_waitcnt vmcnt(8)" ::: "memory");
    } else {
      asm volatile("s_waitcnt vmcnt(0)" ::: "memory");
    }
    __builtin_amdgcn_sched_barrier(0);
    __builtin_amdgcn_s_barrier();
    __builtin_amdgcn_sched_barrier(0);
#pragma unroll
    for (int s = 0; s < 2; ++s) {
      s8v af[MT], bf[NT];
#pragma unroll
      for (int t = 0; t < MT; ++t) {
        int am = wm + t * 16 + l16;
        int ac = (s * 4 + quad) ^ (am & 7);
        af[t] = *(const s8v*)(&lsA[b][am * 64 + ac * 8]);
      }
#pragma unroll
      for (int t = 0; t < NT; ++t) {
        int bn = wn + t * 16 + l16;
        int bc = (s * 4 + quad) ^ (bn & 7);
        bf[t] = *(const s8v*)(&lsB[b][bn * 64 + bc * 8]);
      }
#pragma unroll
      for (int ti = 0; ti < MT; ++ti)
#pragma unroll
        for (int tj = 0; tj < NT; ++tj)
          acc[ti][tj] = __builtin_amdgcn_mfma_f32_16x16x32_bf16(
              af[ti], bf[tj], acc[ti][tj], 0, 0, 0);
    }
    asm volatile("s_waitcnt lgkmcnt(0)" ::: "memory");
    __builtin_amdgcn_sched_barrier(0);
    __builtin_amdgcn_s_barrier();
    __builtin_amdgcn_sched_barrier(0);
  }
#pragma unroll
  for (int tj = 0; tj < NT; ++tj) {
    int col = n0 + wn + tj * 16 + l16;
    float bv = bias[col];
#pragma unroll
    for (int ti = 0; ti < MT; ++ti) {
#pragma unroll
      for (int r = 0; r < 4; ++r) {
        int rowg = m0 + wm + ti * 16 + quad * 4 + r;
        float vv = acc[ti][tj][r] + bv;
        if (KH) vv *= KH_SCALE;
        if (RES == 2) vv += res[(size_t)rowg * N + col];
        if (RELU) vv = fmaxf(vv, 0.f);
        size_t oidx;
        if (KH) {
          int b2 = rowg >> 11, l = rowg & 2047, h = col >> 6, d = col & 63;
          oidx = (((size_t)(b2 * NH + h)) * SEQ + l) * DH + d;
        } else {
          oidx = (size_t)rowg * N + col;
        }
        if (OUTF == 0) ((unsigned short*)out)[oidx] = f2b(vv);
        else           ((float*)out)[oidx] = vv;
      }
    }
  }
}

// ---------------- 256x256 8-phase GEMM (T3+T4+T5), bf16 out + bias (+relu) --
__global__ __launch_bounds__(512, 2) void gemm256(
    const unsigned short* __restrict__ A, const unsigned short* __restrict__ Bt,
    const float* __restrict__ bias, unsigned short* __restrict__ out,
    bool relu, int M, int N, int K) {
  __shared__ __align__(16) unsigned short lsA[2][2][128 * 64];
  __shared__ __align__(16) unsigned short lsB[2][2][128 * 64];
  int tid = threadIdx.x;
  int lane = tid & 63, w = tid >> 6, quad = lane >> 4, l16 = lane & 15;
  int wr = w >> 2, wc = w & 3;
  int bidl = blockIdx.y * (int)gridDim.x + blockIdx.x;
  int swz = xcd_swz(bidl, (int)(gridDim.x * gridDim.y));
  int m0 = (swz / (int)gridDim.x) * 256, n0 = (swz % (int)gridDim.x) * 256;
  f4v acc[8][4] = {};

  auto stageA = [&](int par, int h, int kt) {
#pragma unroll
    for (int i = 0; i < 2; ++i) {
      int cb = w * 128 + i * 64;
      int ci = cb + lane;
      int r = ci >> 3, c = ci & 7;
      int cs = c ^ (r & 7);
      int grow = ((r >> 6) << 7) + h * 64 + (r & 63);
      async16(A + (size_t)(m0 + grow) * K + kt * 64 + cs * 8,
              &lsA[par][h][cb * 8]);
    }
  };
  auto stageB = [&](int par, int h, int kt) {
#pragma unroll
    for (int i = 0; i < 2; ++i) {
      int cb = w * 128 + i * 64;
      int ci = cb + lane;
      int r = ci >> 3, c = ci & 7;
      int cs = c ^ (r & 7);
      int gn = ((r >> 5) << 6) + h * 32 + (r & 31);
      async16(Bt + (size_t)(n0 + gn) * K + kt * 64 + cs * 8,
              &lsB[par][h][cb * 8]);
    }
  };

#define PHASE(PAR, MH, NH, STAGE_STMT, VMN)                                    \
  {                                                                            \
    s8v af[4][2], bf[2][2];                                                    \
    _Pragma("unroll") for (int tm = 0; tm < 4; ++tm) {                         \
      int lr = wr * 64 + tm * 16 + l16;                                        \
      _Pragma("unroll") for (int s = 0; s < 2; ++s) {                          \
        int ac = (s * 4 + quad) ^ (lr & 7);                                    \
        af[tm][s] = *(const s8v*)(&lsA[PAR][MH][lr * 64 + ac * 8]);            \
      }                                                                        \
    }                                                                          \
    _Pragma("unroll") for (int tn = 0; tn < 2; ++tn) {                         \
      int rb = wc * 32 + tn * 16 + l16;                                        \
      _Pragma("unroll") for (int s = 0; s < 2; ++s) {                          \
        int bc = (s * 4 + quad) ^ (rb & 7);                                    \
        bf[tn][s] = *(const s8v*)(&lsB[PAR][NH][rb * 64 + bc * 8]);            \
      }                                                                        \
    }                                                                          \
    STAGE_STMT;                                                                \
    __builtin_amdgcn_sched_barrier(0);                                         \
    __builtin_amdgcn_s_barrier();                                              \
    __builtin_amdgcn_sched_barrier(0);                                         \
    __builtin_amdgcn_s_setprio(1);                                             \
    _Pragma("unroll") for (int s = 0; s < 2; ++s)                              \
      _Pragma("unroll") for (int tm = 0; tm < 4; ++tm)                         \
        _Pragma("unroll") for (int tn = 0; tn < 2; ++tn)                       \
          acc[MH * 4 + tm][NH * 2 + tn] =                                      \
              __builtin_amdgcn_mfma_f32_16x16x32_bf16(                         \
                  af[tm][s], bf[tn][s], acc[MH * 4 + tm][NH * 2 + tn], 0, 0, 0);\
    __builtin_amdgcn_s_setprio(0);                                             \
    __builtin_amdgcn_sched_barrier(0);                                         \
    if (VMN == 4) { asm volatile("s_waitcnt vmcnt(4)" ::: "memory"); }         \
    else if (VMN == 0) { asm volatile("s_waitcnt vmcnt(0)" ::: "memory"); }    \
    __builtin_amdgcn_sched_barrier(0);                                         \
    __builtin_amdgcn_s_barrier();                                              \
    __builtin_amdgcn_sched_barrier(0);                                         \
  }

  int nT = K >> 6;  // assumes nT even, >= 4
  stageA(0, 0, 0); stageB(0, 0, 0); stageA(0, 1, 0); stageB(0, 1, 0);
  stageB(1, 0, 1); stageA(1, 0, 1);
  asm volatile("s_waitcnt vmcnt(4)" ::: "memory");
  __builtin_amdgcn_sched_barrier(0);
  __builtin_amdgcn_s_barrier();
  __builtin_amdgcn_sched_barrier(0);

  for (int t = 0; t < nT; t += 2) {
    bool s2 = (t + 2) < nT, s3 = (t + 3) < nT;
    PHASE(0, 0, 0, { stageA(1, 1, t + 1); }, -1)
    PHASE(0, 1, 0, { stageB(1, 1, t + 1); }, -1)
    PHASE(0, 0, 1, { if (s2) stageB(0, 0, t + 2); }, -1)
    PHASE(0, 1, 1, { if (s2) stageA(0, 0, t + 2); }, (s2 ? 4 : 0))
    PHASE(1, 0, 0, { if (s2) stageA(0, 1, t + 2); }, -1)
    PHASE(1, 1, 0, { if (s2) stageB(0, 1, t + 2); }, -1)
    PHASE(1, 0, 1, { if (s3) stageB(1, 0, t + 3); }, -1)
    PHASE(1, 1, 1, { if (s3) stageA(1, 0, t + 3); }, (s3 ? 4 : 0))
  }
#undef PHASE

#pragma unroll
  for (int mi = 0; mi < 8; ++mi) {
    int mh = mi >> 2, tm = mi & 3;
#pragma unroll
    for (int nj = 0; nj < 4; ++nj) {
      int nh = nj >> 1, tn = nj & 1;
      int col = n0 + wc * 64 + nh * 32 + tn * 16 + l16;
      float bv = bias[col];
#pragma unroll
      for (int r = 0; r < 4; ++r) {
        int rowg = m0 + wr * 128 + mh * 64 + tm * 16 + quad * 4 + r;
        float vv = acc[mi][nj][r] + bv;
        if (relu) vv = fmaxf(vv, 0.f);
        out[(size_t)rowg * N + col] = f2b(vv);
      }
    }
  }
}

// ---------------- proj GEMM with fused attention-combine A-staging ----------
__global__ __launch_bounds__(256) void gemm_proj(
    const unsigned short* __restrict__ Opart, const float* __restrict__ lpart,
    const unsigned short* __restrict__ Bt, const float* __restrict__ bias,
    const float* __restrict__ res, float* __restrict__ out, int M, int N, int K) {
  __shared__ __align__(16) unsigned short lsA[2][64 * 64];
  __shared__ __align__(16) unsigned short lsB[2][64 * 64];
  int tid = threadIdx.x;
  int lane = tid & 63, w = tid >> 6, quad = lane >> 4, l16 = lane & 15;
  int bidl = blockIdx.y * (int)gridDim.x + blockIdx.x;
  int swz = xcd_swz(bidl, (int)(gridDim.x * gridDim.y));
  int m0 = (swz / (int)gridDim.x) * 64, n0 = (swz % (int)gridDim.x) * 64;
  int wm = (w >> 1) * 32, wn = (w & 1) * 32;
  f4v acc[2][2] = {};

  int ci_[2], csA[2], mA[2], b2A[2], lA[2];
#pragma unroll
  for (int i = 0; i < 2; ++i) {
    int cb = w * 128 + i * 64;
    int ci = cb + lane;
    int row = ci >> 3, c = ci & 7;
    ci_[i] = ci; csA[i] = c ^ (row & 7);
    mA[i] = m0 + row; b2A[i] = mA[i] >> 11; lA[i] = mA[i] & 2047;
  }
  s8v o0r[2], o1r[2];
  float lsr0[2], lsr1[2];
  auto issueA = [&](int kt) {
#pragma unroll
    for (int i = 0; i < 2; ++i) {
      const unsigned short* pa =
          Opart + (size_t)mA[i] * D_MODEL + kt * 64 + csA[i] * 8;
      o0r[i] = *(const s8v*)pa;
      o1r[i] = *(const s8v*)(pa + (size_t)MROWS * D_MODEL);
      size_t lidx = ((size_t)b2A[i] * NH + kt) * SEQ + lA[i];
      lsr0[i] = lpart[lidx];
      lsr1[i] = lpart[(size_t)BATCH * NH * SEQ + lidx];
    }
  };
  auto issueB = [&](int bsel, int ktE) {
#pragma unroll
    for (int i = 0; i < 2; ++i) {
      int cb = w * 128 + i * 64;
      int ci = cb + lane;
      int row = ci >> 3, c = ci & 7;
      int cs = c ^ (row & 7);
      async16(Bt + (size_t)(n0 + row) * K + ktE + cs * 8, &lsB[bsel][cb * 8]);
    }
  };
  auto combineWrite = [&](int bsel) {
#pragma unroll
    for (int i = 0; i < 2; ++i) {
      float inv = KH_ISCALE / (lsr0[i] + lsr1[i]);
      float f[8];
#pragma unroll
      for (int j = 0; j < 8; ++j)
        f[j] = (b2f((unsigned short)o0r[i][j]) +
                b2f((unsigned short)o1r[i][j])) * inv;
      s4v lo = cvt4(f[0], f[1], f[2], f[3]);
      s4v hi = cvt4(f[4], f[5], f[6], f[7]);
      s8v vv = {lo[0], lo[1], lo[2], lo[3], hi[0], hi[1], hi[2], hi[3]};
      *(s8v*)(&lsA[bsel][ci_[i] * 8]) = vv;
    }
  };

  issueA(0); issueB(0, 0);
  __builtin_amdgcn_sched_barrier(0);
  asm volatile("s_waitcnt vmcnt(2)" ::: "memory");
  __builtin_amdgcn_sched_barrier(0);
  combineWrite(0);
  asm volatile("s_waitcnt lgkmcnt(0)" ::: "memory");
  __builtin_amdgcn_sched_barrier(0);

  int nK = K >> 6;
  for (int kt = 0; kt < nK; ++kt) {
    int b = kt & 1;
    if (kt + 1 < nK) {
      issueA(kt + 1); issueB(b ^ 1, (kt + 1) << 6);
      __builtin_amdgcn_sched_barrier(0);
      asm volatile("s_waitcnt vmcnt(10)" ::: "memory");
    } else {
      __builtin_amdgcn_sched_barrier(0);
      asm volatile("s_waitcnt vmcnt(0)" ::: "memory");
    }
    __builtin_amdgcn_sched_barrier(0);
    __builtin_amdgcn_s_barrier();
    __builtin_amdgcn_sched_barrier(0);
#pragma unroll
    for (int s = 0; s < 2; ++s) {
      s8v af[2], bf[2];
#pragma unroll
      for (int t = 0; t < 2; ++t) {
        int am = wm + t * 16 + l16;
        int ac = (s * 4 + quad) ^ (am & 7);
        af[t] = *(const s8v*)(&lsA[b][am * 64 + ac * 8]);
      }
#pragma unroll
      for (int t = 0; t < 2; ++t) {
        int bn = wn + t * 16 + l16;
        int bc = (s * 4 + quad) ^ (bn & 7);
        bf[t] = *(const s8v*)(&lsB[b][bn * 64 + bc * 8]);
      }
#pragma unroll
      for (int ti = 0; ti < 2; ++ti)
#pragma unroll
        for (int tj = 0; tj < 2; ++tj)
          acc[ti][tj] = __builtin_amdgcn_mfma_f32_16x16x32_bf16(
              af[ti], bf[tj], acc[ti][tj], 0, 0, 0);
    }
    if (kt + 1 < nK) {
      __builtin_amdgcn_sched_barrier(0);
      asm volatile("s_waitcnt vmcnt(2)" ::: "memory");
      __builtin_amdgcn_sched_barrier(0);
      combineWrite(b ^ 1);
    }
    asm volatile("s_waitcnt lgkmcnt(0)" ::: "memory");
    __builtin_amdgcn_sched_barrier(0);
    __builtin_amdgcn_s_barrier();
    __builtin_amdgcn_sched_barrier(0);
  }
#pragma unroll
  for (int tj = 0; tj < 2; ++tj) {
    int col = n0 + wn + tj * 16 + l16;
    float bv = bias[col];
#pragma unroll
    for (int ti = 0; ti < 2; ++ti) {
#pragma unroll
      for (int r = 0; r < 4; ++r) {
        int rowg = m0 + wm + ti * 16 + quad * 4 + r;
        float vv = acc[ti][tj][r] + bv + res[(size_t)rowg * N + col];
        out[(size_t)rowg * N + col] = vv;
      }
    }
  }
}

// ---------------- fused flash attention, tr-read V, register-P, XCD-local ---
// grid (split=2, bh=32, qb=16); per-XCD working set 8 pairs x 256KB = 2MB.
// lsK subtiled [4 dblk][128 key][16 d], double-buffered. kf reads natural
// stride-32B; V fragments via ds_read_b64_tr_b16 (one base reg, folded adds).
// S^T = mfma(K,Q); exp'd C-frag IS a K=16 A-operand (register P).
__global__ __launch_bounds__(256) void flash_k(
    const unsigned short* __restrict__ kh,
    unsigned short* __restrict__ Opart, float* __restrict__ lpart) {
  __shared__ __align__(16) unsigned short lsK[2][8192];  // 2x16KB subtiled
  int tid = threadIdx.x;
  int lane = tid & 63, w = tid >> 6, quad = lane >> 4, l16 = lane & 15;
  int split = blockIdx.x, bh = blockIdx.y, qb = blockIdx.z;
  const unsigned short* khB = kh + (size_t)bh * SEQ * DH;
  unsigned short* Op = Opart + (size_t)split * MROWS * D_MODEL;
  float* lp = lpart + (size_t)split * BATCH * NH * SEQ;
  s8v aQ[2][2];
#pragma unroll
  for (int g = 0; g < 2; ++g) {
    int q = qb * 128 + w * 32 + g * 16 + l16;
#pragma unroll
    for (int s = 0; s < 2; ++s)
      aQ[g][s] = *(const s8v*)(khB + (size_t)q * DH + s * 32 + quad * 8);
  }
  const s8v vone8 = {(short)0x3F80, (short)0x3F80, (short)0x3F80, (short)0x3F80,
                     (short)0x3F80, (short)0x3F80, (short)0x3F80, (short)0x3F80};
  f4v accO[2][4] = {};
  f4v accL[2] = {};  // row q = quad*4+r (col-replicated), l-sums via MFMA

  // staging: LDS chunk ci -> (dblk=ci>>8, key=(ci>>1)&127, c8=ci&1);
  // source = khB[(key0+key)*64 + dblk*16 + c8*8]
  auto stageK = [&](int bsel, int key0) {
#pragma unroll
    for (int i = 0; i < 4; ++i) {
      int ci = w * 256 + i * 64 + lane;
      async16(khB + (size_t)(key0 + ((ci >> 1) & 127)) * DH +
                  (ci >> 8) * 16 + (ci & 1) * 8,
              &lsK[bsel][(w * 256 + i * 64) * 8]);
    }
  };
  // tr-read base: natural per-lane addr = base + lane*8B (m156 model)
  lds_cp ls0 = (lds_cp)&lsK[0][0];
  lds_cp trb = ls0 + quad * 64 + l16 * 4;  // elements

  stageK(0, split * 1024);
  for (int kt8 = 0; kt8 < 8; ++kt8) {
    int b = kt8 & 1;
    if (kt8 + 1 < 8) {
      stageK(b ^ 1, split * 1024 + (kt8 + 1) * 128);
      asm volatile("s_waitcnt vmcnt(4)" ::: "memory");
    } else {
      asm volatile("s_waitcnt vmcnt(0)" ::: "memory");
    }
    __builtin_amdgcn_sched_barrier(0);
    __builtin_amdgcn_s_barrier();
    __builtin_amdgcn_sched_barrier(0);
#pragma unroll
    for (int half = 0; half < 2; ++half) {
      // S^T = K @ Q^T over 64 keys (lane = key within sub-tile)
      f4v accST[2][4] = {};
#pragma unroll
      for (int s = 0; s < 2; ++s) {
#pragma unroll
        for (int tj = 0; tj < 4; ++tj) {
          // kf = K[key][s*32+quad*8 ..+8], subtiled addr
          s8v kf = *(const s8v*)(&lsK[b][(2 * s + (quad >> 1)) * 2048 +
                                         (half * 64 + tj * 16 + l16) * 16 +
                                         (quad & 1) * 8]);
#pragma unroll
          for (int g = 0; g < 2; ++g)
            accST[g][tj] = __builtin_amdgcn_mfma_f32_16x16x32_bf16(
                kf, aQ[g][s], accST[g][tj], 0, 0, 0);
        }
      }
      // exp in-register -> P A-frags; V via tr-read; l via paired K=32 MFMA
      s4v pprev[2];
#pragma unroll
      for (int tj = 0; tj < 4; ++tj) {
        // issue the 4 V tr-reads first (latency hides under exp/cvt)
        s4v vt[4];
#pragma unroll
        for (int db = 0; db < 4; ++db)
          vt[db] = tr16(trb + b * 8192 + db * 2048 + half * 1024 + tj * 256);
        s4v pf[2];
#pragma unroll
        for (int g = 0; g < 2; ++g) {
          float p0 = xp2(accST[g][tj][0]);
          float p1 = xp2(accST[g][tj][1]);
          float p2 = xp2(accST[g][tj][2]);
          float p3 = xp2(accST[g][tj][3]);
          pf[g] = cvt4(p0, p1, p2, p3);
        }
        if (tj & 1) {
#pragma unroll
          for (int g = 0; g < 2; ++g) {
            s8v pp = {pprev[g][0], pprev[g][1], pprev[g][2], pprev[g][3],
                      pf[g][0], pf[g][1], pf[g][2], pf[g][3]};
            accL[g] = __builtin_amdgcn_mfma_f32_16x16x32_bf16(
                pp, vone8, accL[g], 0, 0, 0);  // B=1: k-position irrelevant
          }
        } else {
#pragma unroll
          for (int g = 0; g < 2; ++g) pprev[g] = pf[g];
        }
        asm volatile("s_waitcnt lgkmcnt(0)" ::: "memory");  // tr reads landed
        __builtin_amdgcn_sched_barrier(0);
#pragma unroll
        for (int db = 0; db < 4; ++db)
#pragma unroll
          for (int g = 0; g < 2; ++g)
            accO[g][db] = mfma16(pf[g], vt[db], accO[g][db]);
      }
    }
    asm volatile("s_waitcnt lgkmcnt(0)" ::: "memory");
    __builtin_amdgcn_sched_barrier(0);
    __builtin_amdgcn_s_barrier();
    __builtin_amdgcn_sched_barrier(0);
  }
  int b = bh >> 4, h = bh & 15;
#pragma unroll
  for (int g = 0; g < 2; ++g) {
    if (l16 == 0) {
#pragma unroll
      for (int r = 0; r < 4; ++r) {
        int q = qb * 128 + w * 32 + g * 16 + quad * 4 + r;
        lp[(size_t)bh * SEQ + q] = accL[g][r];
      }
    }
#pragma unroll
    for (int r = 0; r < 4; ++r) {
      int l = qb * 128 + w * 32 + g * 16 + quad * 4 + r;
#pragma unroll
      for (int db = 0; db < 4; ++db) {
        int d = db * 16 + l16;
        Op[((size_t)(b * SEQ + l)) * D_MODEL + h * DH + d] = f2b(accO[g][db][r]);
      }
    }
  }
}

// ---------------------------------------------------------------------------
extern "C" void kernel_launch(void* const* d_in, const int* in_sizes, int n_in,
                              void* d_out, int out_size, void* d_ws, size_t ws_size,
                              hipStream_t stream) {
  (void)in_sizes; (void)n_in; (void)out_size;
  const float* x      = (const float*)d_in[0];
  const float* w_attn = (const float*)d_in[1];
  const float* b_attn = (const float*)d_in[2];
  const float* w_proj = (const float*)d_in[3];
  const float* b_proj = (const float*)d_in[4];
  const float* ln1_g  = (const float*)d_in[5];
  const float* ln1_b  = (const float*)d_in[6];
  const float* ln2_g  = (const float*)d_in[7];
  const float* ln2_b  = (const float*)d_in[8];
  const float* w_fc1  = (const float*)d_in[9];
  const float* b_fc1  = (const float*)d_in[10];
  const float* w_fc2  = (const float*)d_in[11];
  const float* b_fc2  = (const float*)d_in[12];

  char* ws = (char*)d_ws;
  unsigned short* Opart = (unsigned short*)ws;                         // [0,16M)
  unsigned short* kh    = (unsigned short*)(ws + (size_t)(16u << 20)); // [16,24)
  float*          x1    = (float*)(ws + (size_t)(32u << 20));          // [32,48)
  unsigned short* hbuf  = (unsigned short*)(ws + (size_t)(48u << 20)); // [48,56)
  float*          lpart = (float*)(ws + (size_t)(48u << 20));  // h1 dead by flash
  float* outf = (float*)d_out;
  bool big_ws = ws_size >= ((size_t)72u << 20);

  unsigned short* wTk;
  unsigned short* wTp;
  unsigned short* wTf1;
  unsigned short* wTf2;
  unsigned short* fc1o;
  if (big_ws) {
    wTk  = (unsigned short*)(ws + (size_t)(56u << 20));
    wTp  = wTk;
    wTf1 = wTk;
    wTf2 = (unsigned short*)(ws + (size_t)(64u << 20));
    fc1o = (unsigned short*)ws;                            // [0,32): Op/kh dead
  } else {
    wTk  = (unsigned short*)ws;
    wTp  = (unsigned short*)(ws + (size_t)(24u << 20));    // free (was khT)
    wTf1 = (unsigned short*)ws;
    wTf2 = (unsigned short*)(ws + (size_t)(8u << 20));
    fc1o = kh;                                             // [16,32): chunked 16MB
  }

  dim3 blk(256);
  // 1. h1 = LN1(x)
  hipLaunchKernelGGL(ln_kernel, dim3(MROWS), blk, 0, stream, x, ln1_g, ln1_b, hbuf);
  // 2. wTk = (w_attn[:, 1024:2048])^T
  hipLaunchKernelGGL(transpose_b<float>, dim3(16, 16, 1), blk, 0, stream,
                     w_attn + 1024, wTk, 3 * D_MODEL, D_MODEL, 0LL, 0LL);
  // 3. kh[b,h,l,d] = (h1 @ w_k + b_k) * KH_SCALE
  hipLaunchKernelGGL((gemm_bt<0, false, true, 0, 64, 64>), dim3(16, 64), blk, 0,
                     stream, hbuf, wTk, b_attn + 1024, nullptr, (void*)kh,
                     MROWS, D_MODEL, D_MODEL);
  // 4. flash (tr-read V; khT eliminated) -> bf16 partials + l partials
  hipLaunchKernelGGL(flash_k, dim3(2, 32, SEQ / 128), blk, 0, stream,
                     kh, Opart, lpart);
  // 5. wTp = w_proj^T ; x1 = combine(Opart,lpart) @ w_proj + b + x  (fused)
  hipLaunchKernelGGL(transpose_b<float>, dim3(16, 16, 1), blk, 0, stream,
                     w_proj, wTp, D_MODEL, D_MODEL, 0LL, 0LL);
  hipLaunchKernelGGL(gemm_proj, dim3(16, 64), blk, 0, stream,
                     Opart, lpart, wTp, b_proj, x, x1,
                     MROWS, D_MODEL, D_MODEL);
  // 6. h2 = LN2(x1)
  hipLaunchKernelGGL(ln_kernel, dim3(MROWS), blk, 0, stream, x1, ln2_g, ln2_b, hbuf);
  // 7. wTf1 = w_fc1^T ; wTf2 = w_fc2^T
  hipLaunchKernelGGL(transpose_b<float>, dim3(64, 16, 1), blk, 0, stream,
                     w_fc1, wTf1, 4 * D_MODEL, D_MODEL, 0LL, 0LL);
  hipLaunchKernelGGL(transpose_b<float>, dim3(16, 64, 1), blk, 0, stream,
                     w_fc2, wTf2, D_MODEL, 4 * D_MODEL, 0LL, 0LL);
  // 8/9. FFN: FC1 8-phase 256^2 (256 blocks = 1/CU); FC2 BM=64 (1024 blocks)
  if (big_ws) {
    hipLaunchKernelGGL(gemm256, dim3(16, 16), dim3(512), 0, stream,
                       hbuf, wTf1, b_fc1, fc1o, true,
                       MROWS, 4 * D_MODEL, D_MODEL);
    hipLaunchKernelGGL((gemm_bt<2, false, false, 1, 64, 64>), dim3(16, 64), blk, 0,
                       stream, fc1o, wTf2, b_fc2, x1, (void*)outf,
                       MROWS, D_MODEL, 4 * D_MODEL);
  } else {
    for (int c = 0; c < 2; ++c) {
      const unsigned short* h2c = hbuf + (size_t)c * 2048 * D_MODEL;
      const float* x1c = x1 + (size_t)c * 2048 * D_MODEL;
      float* outc = outf + (size_t)c * 2048 * D_MODEL;
      hipLaunchKernelGGL((gemm_bt<0, true, false, 0, 128, 64>), dim3(64, 16), blk, 0,
                         stream, h2c, wTf1, b_fc1, nullptr, (void*)fc1o,
                         2048, 4 * D_MODEL, D_MODEL);
      hipLaunchKernelGGL((gemm_bt<2, false, false, 1, 64, 64>), dim3(16, 32), blk, 0,
                         stream, fc1o, wTf2, b_fc2, x1c, (void*)outc,
                         2048, D_MODEL, 4 * D_MODEL);
    }
  }
}

// Round 8
// 315.236 us; speedup vs baseline: 1.0834x; 1.0185x over previous
//
#include <hip/hip_runtime.h>

// ---------------------------------------------------------------------------
// Transformer block on MI355X. fp32 I/O (per reference), bf16 MFMA internals,
// fp32 accumulation/residuals.
// R17: gemm256 fragment-residency fix. R16 post-mortem: gemm256 at 20%
// MfmaUtil, ~2480 cyc/phase vs m201's ~825; cause = 12 ds_read_b128/phase
// (A re-read per NH, B re-read per MH) = 96KB/phase -> LDS-read-bound phases.
// Fix: read af[MH] once (ph1/ph2), bf[NH] once (ph1/ph3), HOLD in registers
// across reusing phases (afh/bfh, +96 VGPR, ~340 unified incl 128 AGPR acc,
// below 450 no-spill line). Stage order / vmcnt / barriers byte-identical to
// R14 (proven); WAR re-verified under earlier read-completion times.
// R15/16 kept: flash tr-read V (khT eliminated), lsK dbuf vmcnt(4), accL via
// paired K=32 MFMA. R14: 8-phase 256^2 (T3+T4+T5). R13: XCD-chunk swizzle,
// fused combine-proj. R12: BM=64 N=1024 GEMMs. R11: 2-phase dbuf. R10: kexp
// in kh, cvt_pk, bare exp2. R9: XCD-local flash grid.
// ws layout (56MB min, 72MB preferred):
//   [0,16M)  Opart | big: fc1o [0,32M) after proj
//   [16,24M) kh    | fallback: fc1o [16,32M)
//   [24,32M) (free; was khT)
//   [32,48M) x1    [48,56M) hbuf + lpart during flash
//   [56,64M) wT1 (big), [64,72M) wT2 (big)
// ---------------------------------------------------------------------------

typedef __attribute__((ext_vector_type(8))) short s8v;  // 8 bf16 raw
typedef __attribute__((ext_vector_type(4))) short s4v;  // 4 bf16 raw
typedef __attribute__((ext_vector_type(4))) float f4v;  // mfma accumulator

#define D_MODEL 1024
#define SEQ 2048
#define BATCH 2
#define NH 16
#define DH 64
#define MROWS (BATCH * SEQ)

#define KH_SCALE 0.42466088f
#define KH_ISCALE 2.3548200f

__device__ __forceinline__ float b2f(unsigned short u) {
  union { unsigned int i; float f; } v; v.i = ((unsigned int)u) << 16; return v.f;
}
__device__ __forceinline__ unsigned short f2b(float f) {
  unsigned int i = __builtin_bit_cast(unsigned int, f);
  unsigned int r = (i + 0x7fffu + ((i >> 16) & 1u)) >> 16;  // RNE
  return (unsigned short)r;
}
// async global->LDS, 16B/lane; dest = wave-uniform base + lane*16 (m104/m108)
__device__ __forceinline__ void async16(const void* g, void* l) {
  __builtin_amdgcn_global_load_lds(
      (const __attribute__((address_space(1))) unsigned int*)g,
      (__attribute__((address_space(3))) unsigned int*)l, 16, 0, 0);
}
__device__ __forceinline__ unsigned short cvt_b(float f) { return f2b(f); }
__device__ __forceinline__ unsigned short cvt_b(unsigned short u) { return u; }

__device__ __forceinline__ float xp2(float x) {
#if __has_builtin(__builtin_amdgcn_exp2f)
  return __builtin_amdgcn_exp2f(x);
#else
  return exp2f(x);
#endif
}

// 4x f32 -> packed bf16 s4v via v_cvt_pk_bf16_f32 (RNE, 2 instructions).
__device__ __forceinline__ s4v cvt4(float a, float b, float c, float d) {
  unsigned int lo, hi;
  asm("v_cvt_pk_bf16_f32 %0, %1, %2" : "=v"(lo) : "v"(a), "v"(b));
  asm("v_cvt_pk_bf16_f32 %0, %1, %2" : "=v"(hi) : "v"(c), "v"(d));
  union { unsigned long long u; s4v v; } u;
  u.u = ((unsigned long long)hi << 32) | (unsigned long long)lo;
  return u.v;
}

#if __has_builtin(__builtin_amdgcn_mfma_f32_16x16x16_bf16)
__device__ __forceinline__ f4v mfma16(s4v a, s4v b, f4v c) {
  return __builtin_amdgcn_mfma_f32_16x16x16_bf16(a, b, c, 0, 0, 0);
}
#elif __has_builtin(__builtin_amdgcn_mfma_f32_16x16x16bf16_1k)
__device__ __forceinline__ f4v mfma16(s4v a, s4v b, f4v c) {
  return __builtin_amdgcn_mfma_f32_16x16x16bf16_1k(a, b, c, 0, 0, 0);
}
#else
__device__ __forceinline__ f4v mfma16(s4v a, s4v b, f4v c) {
  s8v aa = {a[0], a[1], a[2], a[3], 0, 0, 0, 0};
  s8v bb = {b[0], b[1], b[2], b[3], 0, 0, 0, 0};
  return __builtin_amdgcn_mfma_f32_16x16x32_bf16(aa, bb, c, 0, 0, 0);
}
#endif

// LDS transpose-read: supply the natural per-lane ds_read_b64 address
// (base + lane*8B); each 16-lane group's 128B region is delivered
// column-major: lane l gets column (l&15) of its 4x16 bf16 tile (m156/m162).
typedef __attribute__((address_space(3))) const unsigned short* lds_cp;
__device__ __forceinline__ s4v tr16(lds_cp p) {
  unsigned long long d;
  asm volatile("ds_read_b64_tr_b16 %0, %1" : "=v"(d) : "v"(p));
  return __builtin_bit_cast(s4v, d);
}

// XCD-chunked logical block id (T1); bijective only when nwg%8==0.
__device__ __forceinline__ int xcd_swz(int bidl, int nwg) {
  return (nwg & 7) ? bidl : ((bidl & 7) * (nwg >> 3) + (bidl >> 3));
}

// ---------------- LayerNorm: fp32 in -> bf16 out, one block per row ---------
__global__ __launch_bounds__(256) void ln_kernel(
    const float* __restrict__ x, const float* __restrict__ g,
    const float* __restrict__ bb, unsigned short* __restrict__ out) {
  int row = blockIdx.x;
  int t = threadIdx.x;
  const float* xr = x + (size_t)row * D_MODEL;
  float v[4];
  float s = 0.f, s2 = 0.f;
#pragma unroll
  for (int i = 0; i < 4; ++i) {
    float f = xr[t + 256 * i];
    v[i] = f; s += f; s2 += f * f;
  }
#pragma unroll
  for (int off = 1; off < 64; off <<= 1) {
    s += __shfl_xor(s, off, 64);
    s2 += __shfl_xor(s2, off, 64);
  }
  __shared__ float red[8];
  if ((t & 63) == 0) { red[t >> 6] = s; red[4 + (t >> 6)] = s2; }
  __syncthreads();
  s = red[0] + red[1] + red[2] + red[3];
  s2 = red[4] + red[5] + red[6] + red[7];
  float mu = s * (1.f / D_MODEL);
  float var = s2 * (1.f / D_MODEL) - mu * mu;
  float rstd = rsqrtf(var + 1e-5f);
#pragma unroll
  for (int i = 0; i < 4; ++i) {
    int c = t + 256 * i;
    float h = (v[i] - mu) * rstd * g[c] + bb[c];
    out[(size_t)row * D_MODEL + c] = f2b(h);
  }
}

// ---------------- batched 64x64 tile transpose -> bf16 ----------------------
template <typename T>
__global__ __launch_bounds__(256) void transpose_b(
    const T* __restrict__ src, unsigned short* __restrict__ dst,
    int srcStride, int dstStride, long long srcBatch, long long dstBatch) {
  __shared__ unsigned short tile[64][65];
  const T* s = src + (size_t)blockIdx.z * srcBatch;
  unsigned short* d = dst + (size_t)blockIdx.z * dstBatch;
  int n0 = blockIdx.x * 64, k0 = blockIdx.y * 64;
  for (int i = threadIdx.x; i < 4096; i += 256) {
    int k = i >> 6, n = i & 63;
    tile[k][n] = cvt_b(s[(size_t)(k0 + k) * srcStride + n0 + n]);
  }
  __syncthreads();
  for (int i = threadIdx.x; i < 4096; i += 256) {
    int n = i >> 6, k = i & 63;
    d[(size_t)(n0 + n) * dstStride + k0 + k] = tile[k][n];
  }
}

// ---------------- GEMM: C[M,N] = A[M,K] @ Bt[N,K]^T + bias (+res)(+relu) ----
// BMxBN tile, BK=64, 4 waves (2x2); 2-phase dbuf, counted vmcnt, raw barrier.
template <int RES, bool RELU, bool KH, int OUTF, int BM, int BN>
__global__ __launch_bounds__(256) void gemm_bt(
    const unsigned short* __restrict__ A, const unsigned short* __restrict__ Bt,
    const float* __restrict__ bias, const float* __restrict__ res,
    void* __restrict__ out, int M, int N, int K) {
  constexpr int MT = BM / 32;
  constexpr int NT = BN / 32;
  __shared__ __align__(16) unsigned short lsA[2][BM * 64];
  __shared__ __align__(16) unsigned short lsB[2][BN * 64];
  int tid = threadIdx.x;
  int lane = tid & 63, w = tid >> 6, quad = lane >> 4, l16 = lane & 15;
  int bidl = blockIdx.y * (int)gridDim.x + blockIdx.x;
  int swz = xcd_swz(bidl, (int)(gridDim.x * gridDim.y));
  int m0 = (swz / (int)gridDim.x) * BM, n0 = (swz % (int)gridDim.x) * BN;
  int wm = (w >> 1) * (BM / 2), wn = (w & 1) * (BN / 2);
  f4v acc[MT][NT] = {};

  auto stage = [&](int bsel, int ktE) {
#pragma unroll
    for (int i = 0; i < MT; ++i) {
      int cb = w * (BM * 2) + i * 64;
      int ci = cb + lane;
      int row = ci >> 3, c = ci & 7;
      int cs = c ^ (row & 7);
      async16(A + (size_t)(m0 + row) * K + ktE + cs * 8, &lsA[bsel][cb * 8]);
    }
#pragma unroll
    for (int i = 0; i < NT; ++i) {
      int cb = w * (BN * 2) + i * 64;
      int ci = cb + lane;
      int row = ci >> 3, c = ci & 7;
      int cs = c ^ (row & 7);
      async16(Bt + (size_t)(n0 + row) * K + ktE + cs * 8, &lsB[bsel][cb * 8]);
    }
  };

  stage(0, 0);
  int nK = K >> 6;
  for (int kt = 0; kt < nK; ++kt) {
    int b = kt & 1;
    if (kt + 1 < nK) {
      stage(b ^ 1, (kt + 1) << 6);
      if constexpr (MT + NT == 4)      asm volatile("s_waitcnt vmcnt(4)" ::: "memory");
      else if constexpr (MT + NT == 6) asm volatile("s_waitcnt vmcnt(6)" ::: "memory");
      else                             asm volatile("s_waitcnt vmcnt(8)" ::: "memory");
    } else {
      asm volatile("s_waitcnt vmcnt(0)" ::: "memory");
    }
    __builtin_amdgcn_sched_barrier(0);
    __builtin_amdgcn_s_barrier();
    __builtin_amdgcn_sched_barrier(0);
#pragma unroll
    for (int s = 0; s < 2; ++s) {
      s8v af[MT], bf[NT];
#pragma unroll
      for (int t = 0; t < MT; ++t) {
        int am = wm + t * 16 + l16;
        int ac = (s * 4 + quad) ^ (am & 7);
        af[t] = *(const s8v*)(&lsA[b][am * 64 + ac * 8]);
      }
#pragma unroll
      for (int t = 0; t < NT; ++t) {
        int bn = wn + t * 16 + l16;
        int bc = (s * 4 + quad) ^ (bn & 7);
        bf[t] = *(const s8v*)(&lsB[b][bn * 64 + bc * 8]);
      }
#pragma unroll
      for (int ti = 0; ti < MT; ++ti)
#pragma unroll
        for (int tj = 0; tj < NT; ++tj)
          acc[ti][tj] = __builtin_amdgcn_mfma_f32_16x16x32_bf16(
              af[ti], bf[tj], acc[ti][tj], 0, 0, 0);
    }
    asm volatile("s_waitcnt lgkmcnt(0)" ::: "memory");
    __builtin_amdgcn_sched_barrier(0);
    __builtin_amdgcn_s_barrier();
    __builtin_amdgcn_sched_barrier(0);
  }
#pragma unroll
  for (int tj = 0; tj < NT; ++tj) {
    int col = n0 + wn + tj * 16 + l16;
    float bv = bias[col];
#pragma unroll
    for (int ti = 0; ti < MT; ++ti) {
#pragma unroll
      for (int r = 0; r < 4; ++r) {
        int rowg = m0 + wm + ti * 16 + quad * 4 + r;
        float vv = acc[ti][tj][r] + bv;
        if (KH) vv *= KH_SCALE;
        if (RES == 2) vv += res[(size_t)rowg * N + col];
        if (RELU) vv = fmaxf(vv, 0.f);
        size_t oidx;
        if (KH) {
          int b2 = rowg >> 11, l = rowg & 2047, h = col >> 6, d = col & 63;
          oidx = (((size_t)(b2 * NH + h)) * SEQ + l) * DH + d;
        } else {
          oidx = (size_t)rowg * N + col;
        }
        if (OUTF == 0) ((unsigned short*)out)[oidx] = f2b(vv);
        else           ((float*)out)[oidx] = vv;
      }
    }
  }
}

// ---------------- 256x256 8-phase GEMM (T3+T4+T5), bf16 out + bias (+relu) --
// R17: fragments are register-resident across reusing phases. af[MH] read at
// MH's first phase (ph1/ph2), bf[NH] at NH's first phase (ph1/ph3); ph4/ph8
// read nothing. 24 ds_read_b128 per K-tile (was 48). Stage order + vmcnt +
// barriers identical to R14 (WAR-safe: every stage's buffer had its last
// reader >=1 barrier earlier under the new read times).
__global__ __launch_bounds__(512, 2) void gemm256(
    const unsigned short* __restrict__ A, const unsigned short* __restrict__ Bt,
    const float* __restrict__ bias, unsigned short* __restrict__ out,
    bool relu, int M, int N, int K) {
  __shared__ __align__(16) unsigned short lsA[2][2][128 * 64];
  __shared__ __align__(16) unsigned short lsB[2][2][128 * 64];
  int tid = threadIdx.x;
  int lane = tid & 63, w = tid >> 6, quad = lane >> 4, l16 = lane & 15;
  int wr = w >> 2, wc = w & 3;
  int bidl = blockIdx.y * (int)gridDim.x + blockIdx.x;
  int swz = xcd_swz(bidl, (int)(gridDim.x * gridDim.y));
  int m0 = (swz / (int)gridDim.x) * 256, n0 = (swz % (int)gridDim.x) * 256;
  f4v acc[8][4] = {};
  s8v afh[2][4][2];  // held A fragments [MH][tm][s]
  s8v bfh[2][2][2];  // held B fragments [NH][tn][s]

  auto stageA = [&](int par, int h, int kt) {
#pragma unroll
    for (int i = 0; i < 2; ++i) {
      int cb = w * 128 + i * 64;
      int ci = cb + lane;
      int r = ci >> 3, c = ci & 7;
      int cs = c ^ (r & 7);
      int grow = ((r >> 6) << 7) + h * 64 + (r & 63);
      async16(A + (size_t)(m0 + grow) * K + kt * 64 + cs * 8,
              &lsA[par][h][cb * 8]);
    }
  };
  auto stageB = [&](int par, int h, int kt) {
#pragma unroll
    for (int i = 0; i < 2; ++i) {
      int cb = w * 128 + i * 64;
      int ci = cb + lane;
      int r = ci >> 3, c = ci & 7;
      int cs = c ^ (r & 7);
      int gn = ((r >> 5) << 6) + h * 32 + (r & 31);
      async16(Bt + (size_t)(n0 + gn) * K + kt * 64 + cs * 8,
              &lsB[par][h][cb * 8]);
    }
  };

// Phase: (optional) read af/bf into held regs, issue stage, barrier,
// 16 MFMA setprio-wrapped from HELD regs, optional counted vmcnt, barrier.
// PAR/MH/NH/RA/RB literal -> static indexing (rule #20).
#define PHASE(PAR, MH, NH, RA, RB, STAGE_STMT, VMN)                            \
  {                                                                            \
    if (RA) {                                                                  \
      _Pragma("unroll") for (int tm = 0; tm < 4; ++tm) {                       \
        int lr = wr * 64 + tm * 16 + l16;                                      \
        _Pragma("unroll") for (int s = 0; s < 2; ++s) {                        \
          int ac = (s * 4 + quad) ^ (lr & 7);                                  \
          afh[MH][tm][s] = *(const s8v*)(&lsA[PAR][MH][lr * 64 + ac * 8]);     \
        }                                                                      \
      }                                                                        \
    }                                                                          \
    if (RB) {                                                                  \
      _Pragma("unroll") for (int tn = 0; tn < 2; ++tn) {                       \
        int rb = wc * 32 + tn * 16 + l16;                                      \
        _Pragma("unroll") for (int s = 0; s < 2; ++s) {                        \
          int bc = (s * 4 + quad) ^ (rb & 7);                                  \
          bfh[NH][tn][s] = *(const s8v*)(&lsB[PAR][NH][rb * 64 + bc * 8]);     \
        }                                                                      \
      }                                                                        \
    }                                                                          \
    STAGE_STMT;                                                                \
    __builtin_amdgcn_sched_barrier(0);                                         \
    __builtin_amdgcn_s_barrier();                                              \
    __builtin_amdgcn_sched_barrier(0);                                         \
    __builtin_amdgcn_s_setprio(1);                                             \
    _Pragma("unroll") for (int s = 0; s < 2; ++s)                              \
      _Pragma("unroll") for (int tm = 0; tm < 4; ++tm)                         \
        _Pragma("unroll") for (int tn = 0; tn < 2; ++tn)                       \
          acc[MH * 4 + tm][NH * 2 + tn] =                                      \
              __builtin_amdgcn_mfma_f32_16x16x32_bf16(                         \
                  afh[MH][tm][s], bfh[NH][tn][s],                              \
                  acc[MH * 4 + tm][NH * 2 + tn], 0, 0, 0);                     \
    __builtin_amdgcn_s_setprio(0);                                             \
    __builtin_amdgcn_sched_barrier(0);                                         \
    if (VMN == 4) { asm volatile("s_waitcnt vmcnt(4)" ::: "memory"); }         \
    else if (VMN == 0) { asm volatile("s_waitcnt vmcnt(0)" ::: "memory"); }    \
    __builtin_amdgcn_sched_barrier(0);                                         \
    __builtin_amdgcn_s_barrier();                                              \
    __builtin_amdgcn_sched_barrier(0);                                         \
  }

  int nT = K >> 6;  // assumes nT even, >= 4
  stageA(0, 0, 0); stageB(0, 0, 0); stageA(0, 1, 0); stageB(0, 1, 0);
  stageB(1, 0, 1); stageA(1, 0, 1);
  asm volatile("s_waitcnt vmcnt(4)" ::: "memory");
  __builtin_amdgcn_sched_barrier(0);
  __builtin_amdgcn_s_barrier();
  __builtin_amdgcn_sched_barrier(0);

  for (int t = 0; t < nT; t += 2) {
    bool s2 = (t + 2) < nT, s3 = (t + 3) < nT;
    PHASE(0, 0, 0, 1, 1, { stageA(1, 1, t + 1); }, -1)                 // ph1
    PHASE(0, 1, 0, 1, 0, { stageB(1, 1, t + 1); }, -1)                 // ph2
    PHASE(0, 0, 1, 0, 1, { if (s2) stageB(0, 0, t + 2); }, -1)         // ph3
    PHASE(0, 1, 1, 0, 0, { if (s2) stageA(0, 0, t + 2); }, (s2 ? 4 : 0)) // ph4
    PHASE(1, 0, 0, 1, 1, { if (s2) stageA(0, 1, t + 2); }, -1)         // ph5
    PHASE(1, 1, 0, 1, 0, { if (s2) stageB(0, 1, t + 2); }, -1)         // ph6
    PHASE(1, 0, 1, 0, 1, { if (s3) stageB(1, 0, t + 3); }, -1)         // ph7
    PHASE(1, 1, 1, 0, 0, { if (s3) stageA(1, 0, t + 3); }, (s3 ? 4 : 0)) // ph8
  }
#undef PHASE

#pragma unroll
  for (int mi = 0; mi < 8; ++mi) {
    int mh = mi >> 2, tm = mi & 3;
#pragma unroll
    for (int nj = 0; nj < 4; ++nj) {
      int nh = nj >> 1, tn = nj & 1;
      int col = n0 + wc * 64 + nh * 32 + tn * 16 + l16;
      float bv = bias[col];
#pragma unroll
      for (int r = 0; r < 4; ++r) {
        int rowg = m0 + wr * 128 + mh * 64 + tm * 16 + quad * 4 + r;
        float vv = acc[mi][nj][r] + bv;
        if (relu) vv = fmaxf(vv, 0.f);
        out[(size_t)rowg * N + col] = f2b(vv);
      }
    }
  }
}

// ---------------- proj GEMM with fused attention-combine A-staging ----------
__global__ __launch_bounds__(256) void gemm_proj(
    const unsigned short* __restrict__ Opart, const float* __restrict__ lpart,
    const unsigned short* __restrict__ Bt, const float* __restrict__ bias,
    const float* __restrict__ res, float* __restrict__ out, int M, int N, int K) {
  __shared__ __align__(16) unsigned short lsA[2][64 * 64];
  __shared__ __align__(16) unsigned short lsB[2][64 * 64];
  int tid = threadIdx.x;
  int lane = tid & 63, w = tid >> 6, quad = lane >> 4, l16 = lane & 15;
  int bidl = blockIdx.y * (int)gridDim.x + blockIdx.x;
  int swz = xcd_swz(bidl, (int)(gridDim.x * gridDim.y));
  int m0 = (swz / (int)gridDim.x) * 64, n0 = (swz % (int)gridDim.x) * 64;
  int wm = (w >> 1) * 32, wn = (w & 1) * 32;
  f4v acc[2][2] = {};

  int ci_[2], csA[2], mA[2], b2A[2], lA[2];
#pragma unroll
  for (int i = 0; i < 2; ++i) {
    int cb = w * 128 + i * 64;
    int ci = cb + lane;
    int row = ci >> 3, c = ci & 7;
    ci_[i] = ci; csA[i] = c ^ (row & 7);
    mA[i] = m0 + row; b2A[i] = mA[i] >> 11; lA[i] = mA[i] & 2047;
  }
  s8v o0r[2], o1r[2];
  float lsr0[2], lsr1[2];
  auto issueA = [&](int kt) {
#pragma unroll
    for (int i = 0; i < 2; ++i) {
      const unsigned short* pa =
          Opart + (size_t)mA[i] * D_MODEL + kt * 64 + csA[i] * 8;
      o0r[i] = *(const s8v*)pa;
      o1r[i] = *(const s8v*)(pa + (size_t)MROWS * D_MODEL);
      size_t lidx = ((size_t)b2A[i] * NH + kt) * SEQ + lA[i];
      lsr0[i] = lpart[lidx];
      lsr1[i] = lpart[(size_t)BATCH * NH * SEQ + lidx];
    }
  };
  auto issueB = [&](int bsel, int ktE) {
#pragma unroll
    for (int i = 0; i < 2; ++i) {
      int cb = w * 128 + i * 64;
      int ci = cb + lane;
      int row = ci >> 3, c = ci & 7;
      int cs = c ^ (row & 7);
      async16(Bt + (size_t)(n0 + row) * K + ktE + cs * 8, &lsB[bsel][cb * 8]);
    }
  };
  auto combineWrite = [&](int bsel) {
#pragma unroll
    for (int i = 0; i < 2; ++i) {
      float inv = KH_ISCALE / (lsr0[i] + lsr1[i]);
      float f[8];
#pragma unroll
      for (int j = 0; j < 8; ++j)
        f[j] = (b2f((unsigned short)o0r[i][j]) +
                b2f((unsigned short)o1r[i][j])) * inv;
      s4v lo = cvt4(f[0], f[1], f[2], f[3]);
      s4v hi = cvt4(f[4], f[5], f[6], f[7]);
      s8v vv = {lo[0], lo[1], lo[2], lo[3], hi[0], hi[1], hi[2], hi[3]};
      *(s8v*)(&lsA[bsel][ci_[i] * 8]) = vv;
    }
  };

  issueA(0); issueB(0, 0);
  __builtin_amdgcn_sched_barrier(0);
  asm volatile("s_waitcnt vmcnt(2)" ::: "memory");
  __builtin_amdgcn_sched_barrier(0);
  combineWrite(0);
  asm volatile("s_waitcnt lgkmcnt(0)" ::: "memory");
  __builtin_amdgcn_sched_barrier(0);

  int nK = K >> 6;
  for (int kt = 0; kt < nK; ++kt) {
    int b = kt & 1;
    if (kt + 1 < nK) {
      issueA(kt + 1); issueB(b ^ 1, (kt + 1) << 6);
      __builtin_amdgcn_sched_barrier(0);
      asm volatile("s_waitcnt vmcnt(10)" ::: "memory");
    } else {
      __builtin_amdgcn_sched_barrier(0);
      asm volatile("s_waitcnt vmcnt(0)" ::: "memory");
    }
    __builtin_amdgcn_sched_barrier(0);
    __builtin_amdgcn_s_barrier();
    __builtin_amdgcn_sched_barrier(0);
#pragma unroll
    for (int s = 0; s < 2; ++s) {
      s8v af[2], bf[2];
#pragma unroll
      for (int t = 0; t < 2; ++t) {
        int am = wm + t * 16 + l16;
        int ac = (s * 4 + quad) ^ (am & 7);
        af[t] = *(const s8v*)(&lsA[b][am * 64 + ac * 8]);
      }
#pragma unroll
      for (int t = 0; t < 2; ++t) {
        int bn = wn + t * 16 + l16;
        int bc = (s * 4 + quad) ^ (bn & 7);
        bf[t] = *(const s8v*)(&lsB[b][bn * 64 + bc * 8]);
      }
#pragma unroll
      for (int ti = 0; ti < 2; ++ti)
#pragma unroll
        for (int tj = 0; tj < 2; ++tj)
          acc[ti][tj] = __builtin_amdgcn_mfma_f32_16x16x32_bf16(
              af[ti], bf[tj], acc[ti][tj], 0, 0, 0);
    }
    if (kt + 1 < nK) {
      __builtin_amdgcn_sched_barrier(0);
      asm volatile("s_waitcnt vmcnt(2)" ::: "memory");
      __builtin_amdgcn_sched_barrier(0);
      combineWrite(b ^ 1);
    }
    asm volatile("s_waitcnt lgkmcnt(0)" ::: "memory");
    __builtin_amdgcn_sched_barrier(0);
    __builtin_amdgcn_s_barrier();
    __builtin_amdgcn_sched_barrier(0);
  }
#pragma unroll
  for (int tj = 0; tj < 2; ++tj) {
    int col = n0 + wn + tj * 16 + l16;
    float bv = bias[col];
#pragma unroll
    for (int ti = 0; ti < 2; ++ti) {
#pragma unroll
      for (int r = 0; r < 4; ++r) {
        int rowg = m0 + wm + ti * 16 + quad * 4 + r;
        float vv = acc[ti][tj][r] + bv + res[(size_t)rowg * N + col];
        out[(size_t)rowg * N + col] = vv;
      }
    }
  }
}

// ---------------- fused flash attention, tr-read V, register-P, XCD-local ---
__global__ __launch_bounds__(256) void flash_k(
    const unsigned short* __restrict__ kh,
    unsigned short* __restrict__ Opart, float* __restrict__ lpart) {
  __shared__ __align__(16) unsigned short lsK[2][8192];  // 2x16KB subtiled
  int tid = threadIdx.x;
  int lane = tid & 63, w = tid >> 6, quad = lane >> 4, l16 = lane & 15;
  int split = blockIdx.x, bh = blockIdx.y, qb = blockIdx.z;
  const unsigned short* khB = kh + (size_t)bh * SEQ * DH;
  unsigned short* Op = Opart + (size_t)split * MROWS * D_MODEL;
  float* lp = lpart + (size_t)split * BATCH * NH * SEQ;
  s8v aQ[2][2];
#pragma unroll
  for (int g = 0; g < 2; ++g) {
    int q = qb * 128 + w * 32 + g * 16 + l16;
#pragma unroll
    for (int s = 0; s < 2; ++s)
      aQ[g][s] = *(const s8v*)(khB + (size_t)q * DH + s * 32 + quad * 8);
  }
  const s8v vone8 = {(short)0x3F80, (short)0x3F80, (short)0x3F80, (short)0x3F80,
                     (short)0x3F80, (short)0x3F80, (short)0x3F80, (short)0x3F80};
  f4v accO[2][4] = {};
  f4v accL[2] = {};

  auto stageK = [&](int bsel, int key0) {
#pragma unroll
    for (int i = 0; i < 4; ++i) {
      int ci = w * 256 + i * 64 + lane;
      async16(khB + (size_t)(key0 + ((ci >> 1) & 127)) * DH +
                  (ci >> 8) * 16 + (ci & 1) * 8,
              &lsK[bsel][(w * 256 + i * 64) * 8]);
    }
  };
  lds_cp ls0 = (lds_cp)&lsK[0][0];
  lds_cp trb = ls0 + quad * 64 + l16 * 4;  // elements

  stageK(0, split * 1024);
  for (int kt8 = 0; kt8 < 8; ++kt8) {
    int b = kt8 & 1;
    if (kt8 + 1 < 8) {
      stageK(b ^ 1, split * 1024 + (kt8 + 1) * 128);
      asm volatile("s_waitcnt vmcnt(4)" ::: "memory");
    } else {
      asm volatile("s_waitcnt vmcnt(0)" ::: "memory");
    }
    __builtin_amdgcn_sched_barrier(0);
    __builtin_amdgcn_s_barrier();
    __builtin_amdgcn_sched_barrier(0);
#pragma unroll
    for (int half = 0; half < 2; ++half) {
      f4v accST[2][4] = {};
#pragma unroll
      for (int s = 0; s < 2; ++s) {
#pragma unroll
        for (int tj = 0; tj < 4; ++tj) {
          s8v kf = *(const s8v*)(&lsK[b][(2 * s + (quad >> 1)) * 2048 +
                                         (half * 64 + tj * 16 + l16) * 16 +
                                         (quad & 1) * 8]);
#pragma unroll
          for (int g = 0; g < 2; ++g)
            accST[g][tj] = __builtin_amdgcn_mfma_f32_16x16x32_bf16(
                kf, aQ[g][s], accST[g][tj], 0, 0, 0);
        }
      }
      s4v pprev[2];
#pragma unroll
      for (int tj = 0; tj < 4; ++tj) {
        s4v vt[4];
#pragma unroll
        for (int db = 0; db < 4; ++db)
          vt[db] = tr16(trb + b * 8192 + db * 2048 + half * 1024 + tj * 256);
        s4v pf[2];
#pragma unroll
        for (int g = 0; g < 2; ++g) {
          float p0 = xp2(accST[g][tj][0]);
          float p1 = xp2(accST[g][tj][1]);
          float p2 = xp2(accST[g][tj][2]);
          float p3 = xp2(accST[g][tj][3]);
          pf[g] = cvt4(p0, p1, p2, p3);
        }
        if (tj & 1) {
#pragma unroll
          for (int g = 0; g < 2; ++g) {
            s8v pp = {pprev[g][0], pprev[g][1], pprev[g][2], pprev[g][3],
                      pf[g][0], pf[g][1], pf[g][2], pf[g][3]};
            accL[g] = __builtin_amdgcn_mfma_f32_16x16x32_bf16(
                pp, vone8, accL[g], 0, 0, 0);  // B=1: k-position irrelevant
          }
        } else {
#pragma unroll
          for (int g = 0; g < 2; ++g) pprev[g] = pf[g];
        }
        asm volatile("s_waitcnt lgkmcnt(0)" ::: "memory");  // tr reads landed
        __builtin_amdgcn_sched_barrier(0);
#pragma unroll
        for (int db = 0; db < 4; ++db)
#pragma unroll
          for (int g = 0; g < 2; ++g)
            accO[g][db] = mfma16(pf[g], vt[db], accO[g][db]);
      }
    }
    asm volatile("s_waitcnt lgkmcnt(0)" ::: "memory");
    __builtin_amdgcn_sched_barrier(0);
    __builtin_amdgcn_s_barrier();
    __builtin_amdgcn_sched_barrier(0);
  }
  int b = bh >> 4, h = bh & 15;
#pragma unroll
  for (int g = 0; g < 2; ++g) {
    if (l16 == 0) {
#pragma unroll
      for (int r = 0; r < 4; ++r) {
        int q = qb * 128 + w * 32 + g * 16 + quad * 4 + r;
        lp[(size_t)bh * SEQ + q] = accL[g][r];
      }
    }
#pragma unroll
    for (int r = 0; r < 4; ++r) {
      int l = qb * 128 + w * 32 + g * 16 + quad * 4 + r;
#pragma unroll
      for (int db = 0; db < 4; ++db) {
        int d = db * 16 + l16;
        Op[((size_t)(b * SEQ + l)) * D_MODEL + h * DH + d] = f2b(accO[g][db][r]);
      }
    }
  }
}

// ---------------------------------------------------------------------------
extern "C" void kernel_launch(void* const* d_in, const int* in_sizes, int n_in,
                              void* d_out, int out_size, void* d_ws, size_t ws_size,
                              hipStream_t stream) {
  (void)in_sizes; (void)n_in; (void)out_size;
  const float* x      = (const float*)d_in[0];
  const float* w_attn = (const float*)d_in[1];
  const float* b_attn = (const float*)d_in[2];
  const float* w_proj = (const float*)d_in[3];
  const float* b_proj = (const float*)d_in[4];
  const float* ln1_g  = (const float*)d_in[5];
  const float* ln1_b  = (const float*)d_in[6];
  const float* ln2_g  = (const float*)d_in[7];
  const float* ln2_b  = (const float*)d_in[8];
  const float* w_fc1  = (const float*)d_in[9];
  const float* b_fc1  = (const float*)d_in[10];
  const float* w_fc2  = (const float*)d_in[11];
  const float* b_fc2  = (const float*)d_in[12];

  char* ws = (char*)d_ws;
  unsigned short* Opart = (unsigned short*)ws;                         // [0,16M)
  unsigned short* kh    = (unsigned short*)(ws + (size_t)(16u << 20)); // [16,24)
  float*          x1    = (float*)(ws + (size_t)(32u << 20));          // [32,48)
  unsigned short* hbuf  = (unsigned short*)(ws + (size_t)(48u << 20)); // [48,56)
  float*          lpart = (float*)(ws + (size_t)(48u << 20));  // h1 dead by flash
  float* outf = (float*)d_out;
  bool big_ws = ws_size >= ((size_t)72u << 20);

  unsigned short* wTk;
  unsigned short* wTp;
  unsigned short* wTf1;
  unsigned short* wTf2;
  unsigned short* fc1o;
  if (big_ws) {
    wTk  = (unsigned short*)(ws + (size_t)(56u << 20));
    wTp  = wTk;
    wTf1 = wTk;
    wTf2 = (unsigned short*)(ws + (size_t)(64u << 20));
    fc1o = (unsigned short*)ws;                            // [0,32): Op/kh dead
  } else {
    wTk  = (unsigned short*)ws;
    wTp  = (unsigned short*)(ws + (size_t)(24u << 20));    // free (was khT)
    wTf1 = (unsigned short*)ws;
    wTf2 = (unsigned short*)(ws + (size_t)(8u << 20));
    fc1o = kh;                                             // [16,32): chunked 16MB
  }

  dim3 blk(256);
  // 1. h1 = LN1(x)
  hipLaunchKernelGGL(ln_kernel, dim3(MROWS), blk, 0, stream, x, ln1_g, ln1_b, hbuf);
  // 2. wTk = (w_attn[:, 1024:2048])^T
  hipLaunchKernelGGL(transpose_b<float>, dim3(16, 16, 1), blk, 0, stream,
                     w_attn + 1024, wTk, 3 * D_MODEL, D_MODEL, 0LL, 0LL);
  // 3. kh[b,h,l,d] = (h1 @ w_k + b_k) * KH_SCALE
  hipLaunchKernelGGL((gemm_bt<0, false, true, 0, 64, 64>), dim3(16, 64), blk, 0,
                     stream, hbuf, wTk, b_attn + 1024, nullptr, (void*)kh,
                     MROWS, D_MODEL, D_MODEL);
  // 4. flash (tr-read V; khT eliminated) -> bf16 partials + l partials
  hipLaunchKernelGGL(flash_k, dim3(2, 32, SEQ / 128), blk, 0, stream,
                     kh, Opart, lpart);
  // 5. wTp = w_proj^T ; x1 = combine(Opart,lpart) @ w_proj + b + x  (fused)
  hipLaunchKernelGGL(transpose_b<float>, dim3(16, 16, 1), blk, 0, stream,
                     w_proj, wTp, D_MODEL, D_MODEL, 0LL, 0LL);
  hipLaunchKernelGGL(gemm_proj, dim3(16, 64), blk, 0, stream,
                     Opart, lpart, wTp, b_proj, x, x1,
                     MROWS, D_MODEL, D_MODEL);
  // 6. h2 = LN2(x1)
  hipLaunchKernelGGL(ln_kernel, dim3(MROWS), blk, 0, stream, x1, ln2_g, ln2_b, hbuf);
  // 7. wTf1 = w_fc1^T ; wTf2 = w_fc2^T
  hipLaunchKernelGGL(transpose_b<float>, dim3(64, 16, 1), blk, 0, stream,
                     w_fc1, wTf1, 4 * D_MODEL, D_MODEL, 0LL, 0LL);
  hipLaunchKernelGGL(transpose_b<float>, dim3(16, 64, 1), blk, 0, stream,
                     w_fc2, wTf2, D_MODEL, 4 * D_MODEL, 0LL, 0LL);
  // 8/9. FFN: FC1 8-phase 256^2 (256 blocks = 1/CU); FC2 BM=64 (1024 blocks)
  if (big_ws) {
    hipLaunchKernelGGL(gemm256, dim3(16, 16), dim3(512), 0, stream,
                       hbuf, wTf1, b_fc1, fc1o, true,
                       MROWS, 4 * D_MODEL, D_MODEL);
    hipLaunchKernelGGL((gemm_bt<2, false, false, 1, 64, 64>), dim3(16, 64), blk, 0,
                       stream, fc1o, wTf2, b_fc2, x1, (void*)outf,
                       MROWS, D_MODEL, 4 * D_MODEL);
  } else {
    for (int c = 0; c < 2; ++c) {
      const unsigned short* h2c = hbuf + (size_t)c * 2048 * D_MODEL;
      const float* x1c = x1 + (size_t)c * 2048 * D_MODEL;
      float* outc = outf + (size_t)c * 2048 * D_MODEL;
      hipLaunchKernelGGL((gemm_bt<0, true, false, 0, 128, 64>), dim3(64, 16), blk, 0,
                         stream, h2c, wTf1, b_fc1, nullptr, (void*)fc1o,
                         2048, 4 * D_MODEL, D_MODEL);
      hipLaunchKernelGGL((gemm_bt<2, false, false, 1, 64, 64>), dim3(16, 32), blk, 0,
                         stream, fc1o, wTf2, b_fc2, x1c, (void*)outc,
                         2048, D_MODEL, 4 * D_MODEL);
    }
  }
}